// Round 3
// baseline (849.104 us; speedup 1.0000x reference)
//
#include <hip/hip_runtime.h>
#include <math.h>

#define N_NODES 50000
#define N_EDGESC 2000
#define N_INC   200000
#define SEQ     64
#define FEATN   6
#define CH      32
#define OUTF    5
#define SLOPE   0.01f

__device__ __forceinline__ float fast_rcp(float x) { return __builtin_amdgcn_rcpf(x); }
__device__ __forceinline__ float sigm(float x) { return fast_rcp(1.f + __expf(-x)); }
__device__ __forceinline__ float tanh_fast(float x) { return 1.f - 2.f * fast_rcp(1.f + __expf(2.f * x)); }
__device__ __forceinline__ float leaky(float v) { return v > 0.f ? v : SLOPE * v; }

// ---------------- GRU: one wave = 2 nodes, k-split across wave halves ----------------
// Lane layout: lane = 32*half + j.  Half g owns node (pair_base+g)'s hidden state
// h[j], and stores w_hh[*, g*16 : g*16+16] only (48 floats vs 96 -> weights stay
// register-resident; round-2 showed the compiler reloads weights every step when
// the full 96 are needed at VGPR=112).
// Each lane computes k-partials for BOTH nodes (same 96 FMA/step), combined with
// one __shfl_xor(,32) per gate.
__global__ __launch_bounds__(256, 2) void gru_theta_kernel(
    const float* __restrict__ price,
    const float* __restrict__ w_ih, const float* __restrict__ w_hh,
    const float* __restrict__ b_ih, const float* __restrict__ b_hh,
    const float* __restrict__ theta1,
    float* __restrict__ Y)
{
  __shared__ float hbuf[256];
  const int tid  = threadIdx.x;
  const int lane = tid & 63;
  const int half = lane >> 5;           // 0 or 1
  const int j    = lane & 31;           // hidden unit owned by this lane
  const int wb   = tid & ~63;           // wave base in hbuf
  const int gwave = blockIdx.x * 4 + (tid >> 6);
  const int m    = gwave * 2 + half;    // node owned by this half
  const int k0   = half * 16;           // k-range [k0, k0+16)

  // h chunk offsets in hbuf (node A h at wb+0..31, node B h at wb+32..63)
  const int own_off = wb + half * 32 + k0;          // own node's h, my k-range
  const int oth_off = wb + (1 - half) * 32 + k0;    // other node's h, my k-range

  // per-lane recurrent weights: 16 k-values per gate (48 floats)
  float whr[16], whz[16], whn[16];
#pragma unroll
  for (int k4 = 0; k4 < 4; ++k4) {
    float4 a = *(const float4*)(w_hh + (j       ) * CH + k0 + k4 * 4);
    float4 b = *(const float4*)(w_hh + (j + 32  ) * CH + k0 + k4 * 4);
    float4 c = *(const float4*)(w_hh + (j + 64  ) * CH + k0 + k4 * 4);
    whr[4*k4+0]=a.x; whr[4*k4+1]=a.y; whr[4*k4+2]=a.z; whr[4*k4+3]=a.w;
    whz[4*k4+0]=b.x; whz[4*k4+1]=b.y; whz[4*k4+2]=b.z; whz[4*k4+3]=b.w;
    whn[4*k4+0]=c.x; whn[4*k4+1]=c.y; whn[4*k4+2]=c.z; whn[4*k4+3]=c.w;
  }
  // input weights: full rows (own node only), 18 floats
  float wir[FEATN], wiz[FEATN], win[FEATN];
#pragma unroll
  for (int f = 0; f < FEATN; ++f) {
    wir[f] = w_ih[(j      ) * FEATN + f];
    wiz[f] = w_ih[(j + 32 ) * FEATN + f];
    win[f] = w_ih[(j + 64 ) * FEATN + f];
  }
  const float br  = b_ih[j]      + b_hh[j];
  const float bz  = b_ih[j + 32] + b_hh[j + 32];
  const float bin = b_ih[j + 64];
  const float bhn = b_hh[j + 64];

  float h = 0.f;
  const float* xp = price + m * (SEQ * FEATN);

  // software-pipelined x loads (own node)
  float2 x01 = *(const float2*)(xp);
  float2 x23 = *(const float2*)(xp + 2);
  float2 x45 = *(const float2*)(xp + 4);

  for (int t = 0; t < SEQ; ++t) {
    // input-gate part (own node, full rows)
    float gr_o = br + wir[0]*x01.x + wir[1]*x01.y + wir[2]*x23.x
                    + wir[3]*x23.y + wir[4]*x45.x + wir[5]*x45.y;
    float gz_o = bz + wiz[0]*x01.x + wiz[1]*x01.y + wiz[2]*x23.x
                    + wiz[3]*x23.y + wiz[4]*x45.x + wiz[5]*x45.y;
    float i_n = bin + win[0]*x01.x + win[1]*x01.y + win[2]*x23.x
                    + win[3]*x23.y + win[4]*x45.x + win[5]*x45.y;
    float hn_o = bhn;
    float gr_x = 0.f, gz_x = 0.f, hn_x = 0.f;

    // prefetch next step's x
    if (t + 1 < SEQ) {
      const float* nxt = xp + (t + 1) * FEATN;
      x01 = *(const float2*)(nxt);
      x23 = *(const float2*)(nxt + 2);
      x45 = *(const float2*)(nxt + 4);
    }

    hbuf[tid] = h;  // wave-lockstep; in-order DS pipe + may-alias keeps ordering
#pragma unroll
    for (int k4 = 0; k4 < 4; ++k4) {
      float4 ho = *(const float4*)(hbuf + own_off + 4 * k4);  // own node h chunk
      float4 hx = *(const float4*)(hbuf + oth_off + 4 * k4);  // other node h chunk
      gr_o += whr[4*k4+0]*ho.x + whr[4*k4+1]*ho.y;
      gr_o += whr[4*k4+2]*ho.z + whr[4*k4+3]*ho.w;
      gr_x += whr[4*k4+0]*hx.x + whr[4*k4+1]*hx.y;
      gr_x += whr[4*k4+2]*hx.z + whr[4*k4+3]*hx.w;
      gz_o += whz[4*k4+0]*ho.x + whz[4*k4+1]*ho.y;
      gz_o += whz[4*k4+2]*ho.z + whz[4*k4+3]*ho.w;
      gz_x += whz[4*k4+0]*hx.x + whz[4*k4+1]*hx.y;
      gz_x += whz[4*k4+2]*hx.z + whz[4*k4+3]*hx.w;
      hn_o += whn[4*k4+0]*ho.x + whn[4*k4+1]*ho.y;
      hn_o += whn[4*k4+2]*ho.z + whn[4*k4+3]*ho.w;
      hn_x += whn[4*k4+0]*hx.x + whn[4*k4+1]*hx.y;
      hn_x += whn[4*k4+2]*hx.z + whn[4*k4+3]*hx.w;
    }
    // combine partials: my _x partial is the OTHER node's contribution from my
    // k-range; the lane^32 partner's _x partial completes MY node's dot.
    float r  = sigm(gr_o + __shfl_xor(gr_x, 32));
    float z  = sigm(gz_o + __shfl_xor(gz_x, 32));
    float hn = hn_o + __shfl_xor(hn_x, 32);
    float n  = tanh_fast(i_n + r * hn);
    h = (1.f - z) * n + z * h;
  }

  // epilogue: y_j = sum_k h_own[k] * theta1[j,k]
  hbuf[tid] = h;
  const int hfull = wb + half * 32;
  float a0 = 0.f, a1 = 0.f;
#pragma unroll
  for (int k4 = 0; k4 < 8; ++k4) {
    float4 hv = *(const float4*)(hbuf + hfull + 4 * k4);
    float4 tv = *(const float4*)(theta1 + j * CH + 4 * k4);
    a0 += tv.x * hv.x + tv.z * hv.z;
    a1 += tv.y * hv.y + tv.w * hv.w;
  }
  Y[m * CH + j] = a0 + a1;
}

// ---------------- degree counting ----------------
__global__ __launch_bounds__(256) void deg_kernel(
    const int* __restrict__ nodes, const int* __restrict__ edges,
    int* __restrict__ DN, int* __restrict__ DE)
{
  int i = blockIdx.x * 256 + threadIdx.x;
  if (i < N_INC) {
    atomicAdd(&DN[nodes[i]], 1);
    atomicAdd(&DE[edges[i]], 1);
  }
}

// ---------------- exclusive scan of edge degrees (single block) ----------------
__global__ __launch_bounds__(256) void scan_kernel(const int* __restrict__ DE, int* __restrict__ OFF)
{
  __shared__ int part[256];
  int t = threadIdx.x;
  int c[8]; int sum = 0;
#pragma unroll
  for (int u = 0; u < 8; ++u) {
    int idx = t * 8 + u;
    int x = (idx < N_EDGESC) ? DE[idx] : 0;
    c[u] = x; sum += x;
  }
  part[t] = sum;
  __syncthreads();
  for (int d = 1; d < 256; d <<= 1) {
    int v = (t >= d) ? part[t - d] : 0;
    __syncthreads();
    part[t] += v;
    __syncthreads();
  }
  int base = part[t] - sum;  // exclusive
#pragma unroll
  for (int u = 0; u < 8; ++u) {
    int idx = t * 8 + u;
    if (idx <= N_EDGESC) OFF[idx] = base;
    base += c[u];
  }
}

// ---------------- node->edge segmented gather-sum (one block per edge) ----------------
__global__ __launch_bounds__(128) void edge_gather_kernel(
    const float* __restrict__ X, const int* __restrict__ nodes,
    const int* __restrict__ OFF, float* __restrict__ EF)
{
  int e = blockIdx.x;
  int s = OFF[e], tE = OFF[e + 1];
  int f = threadIdx.x & 31, g = threadIdx.x >> 5;
  float acc = 0.f;
  for (int i = s + g; i < tE; i += 4)
    acc += X[nodes[i] * CH + f];
  acc += __shfl_down(acc, 32);
  __shared__ float red[32];
  if (threadIdx.x >= 64 && threadIdx.x < 96) red[f] = acc;
  __syncthreads();
  if (threadIdx.x < 32) {
    int cnt = tE - s;
    float binv = cnt > 0 ? 1.f / (float)cnt : 0.f;
    EF[e * CH + f] = (acc + red[f]) * binv;
  }
}

// ---------------- edge->node scatter (atomic) ----------------
__global__ __launch_bounds__(256) void scatter_kernel(
    const float* __restrict__ EF, const int* __restrict__ nodes,
    const int* __restrict__ edges, float* __restrict__ ACC)
{
  int gid = blockIdx.x * 256 + threadIdx.x;
  if (gid >= N_INC * 8) return;
  int i = gid >> 3, q = gid & 7;
  int e = edges[i], n = nodes[i];
  float4 v = *(const float4*)(EF + e * CH + q * 4);
  float* dst = ACC + n * CH + q * 4;
  unsafeAtomicAdd(dst + 0, v.x);
  unsafeAtomicAdd(dst + 1, v.y);
  unsafeAtomicAdd(dst + 2, v.z);
  unsafeAtomicAdd(dst + 3, v.w);
}

// ---------------- dinv+bias+leaky then theta2 matmul (8 threads per node) ----------------
__global__ __launch_bounds__(256) void fuse_theta_kernel(
    const float* __restrict__ ACC, const int* __restrict__ DN,
    const float* __restrict__ bias, const float* __restrict__ theta,
    float* __restrict__ Yout)
{
  int gid = blockIdx.x * 256 + threadIdx.x;
  if (gid >= N_NODES * 8) return;
  int n = gid >> 3, oq = gid & 7;
  int d = DN[n];
  float dinv = d > 0 ? 1.f / (float)d : 0.f;
  float v[CH];
#pragma unroll
  for (int k4 = 0; k4 < 8; ++k4) {
    float4 a = *(const float4*)(ACC + n * CH + 4 * k4);
    v[4*k4+0] = leaky(fmaf(a.x, dinv, bias[4*k4+0]));
    v[4*k4+1] = leaky(fmaf(a.y, dinv, bias[4*k4+1]));
    v[4*k4+2] = leaky(fmaf(a.z, dinv, bias[4*k4+2]));
    v[4*k4+3] = leaky(fmaf(a.w, dinv, bias[4*k4+3]));
  }
  float o[4];
#pragma unroll
  for (int r = 0; r < 4; ++r) {
    float s0 = 0.f, s1 = 0.f;
#pragma unroll
    for (int k4 = 0; k4 < 8; ++k4) {
      float4 tv = *(const float4*)(theta + (oq * 4 + r) * CH + 4 * k4);
      s0 += tv.x * v[4*k4+0] + tv.z * v[4*k4+2];
      s1 += tv.y * v[4*k4+1] + tv.w * v[4*k4+3];
    }
    o[r] = s0 + s1;
  }
  *(float4*)(Yout + n * CH + oq * 4) = make_float4(o[0], o[1], o[2], o[3]);
}

// ---------------- conv2 finalize + output linear ----------------
__global__ __launch_bounds__(256) void out_kernel(
    const float* __restrict__ ACC, const int* __restrict__ DN,
    const float* __restrict__ bias2, const float* __restrict__ w_out,
    const float* __restrict__ b_out, float* __restrict__ out)
{
  int n = blockIdx.x * 256 + threadIdx.x;
  if (n >= N_NODES) return;
  int d = DN[n];
  float dinv = d > 0 ? 1.f / (float)d : 0.f;
  float v[CH];
#pragma unroll
  for (int k4 = 0; k4 < 8; ++k4) {
    float4 a = *(const float4*)(ACC + n * CH + 4 * k4);
    v[4*k4+0] = leaky(fmaf(a.x, dinv, bias2[4*k4+0]));
    v[4*k4+1] = leaky(fmaf(a.y, dinv, bias2[4*k4+1]));
    v[4*k4+2] = leaky(fmaf(a.z, dinv, bias2[4*k4+2]));
    v[4*k4+3] = leaky(fmaf(a.w, dinv, bias2[4*k4+3]));
  }
#pragma unroll
  for (int o = 0; o < OUTF; ++o) {
    float s = b_out[o];
#pragma unroll
    for (int k = 0; k < CH; ++k) s += v[k] * w_out[o * CH + k];
    out[n * OUTF + o] = leaky(s);
  }
}

extern "C" void kernel_launch(void* const* d_in, const int* in_sizes, int n_in,
                              void* d_out, int out_size, void* d_ws, size_t ws_size,
                              hipStream_t stream)
{
  const float* price   = (const float*)d_in[0];
  const int*   e_nodes = (const int*)d_in[1];
  const int*   e_edges = (const int*)d_in[2];
  // d_in[3]=concept, d_in[4]=volumn, d_in[5]=num_edges : unused by reference math
  const float* w_ih    = (const float*)d_in[6];
  const float* w_hh    = (const float*)d_in[7];
  const float* b_ih    = (const float*)d_in[8];
  const float* b_hh    = (const float*)d_in[9];
  const float* theta1  = (const float*)d_in[10];
  const float* bias1   = (const float*)d_in[11];
  const float* theta2  = (const float*)d_in[12];
  const float* bias2   = (const float*)d_in[13];
  const float* w_out   = (const float*)d_in[14];
  const float* b_out   = (const float*)d_in[15];
  float* out = (float*)d_out;

  float* ws  = (float*)d_ws;
  float* Y   = ws;                 // [50000*32]
  float* ACC = ws + 1600000;       // [50000*32]
  float* EF  = ws + 3200000;       // [2000*32]
  int*   DN  = (int*)(ws + 3264000);  // [50000]
  int*   DE  = DN + N_NODES;          // [2000]
  int*   OFF = DE + N_EDGESC;         // [2001]

  hipMemsetAsync(DN, 0, (N_NODES + N_EDGESC + N_EDGESC + 1) * sizeof(int), stream);
  deg_kernel<<<(N_INC + 255) / 256, 256, 0, stream>>>(e_nodes, e_edges, DN, DE);
  scan_kernel<<<1, 256, 0, stream>>>(DE, OFF);

  // 8 nodes per block (4 waves x 2 nodes) -> 6250 blocks
  gru_theta_kernel<<<N_NODES / 8, 256, 0, stream>>>(
      price, w_ih, w_hh, b_ih, b_hh, theta1, Y);

  // conv1: node->edge, edge->node
  edge_gather_kernel<<<N_EDGESC, 128, 0, stream>>>(Y, e_nodes, OFF, EF);
  hipMemsetAsync(ACC, 0, N_NODES * CH * sizeof(float), stream);
  scatter_kernel<<<(N_INC * 8 + 255) / 256, 256, 0, stream>>>(EF, e_nodes, e_edges, ACC);

  // conv1 finalize + theta2
  fuse_theta_kernel<<<(N_NODES * 8 + 255) / 256, 256, 0, stream>>>(ACC, DN, bias1, theta2, Y);

  // conv2: node->edge, edge->node
  edge_gather_kernel<<<N_EDGESC, 128, 0, stream>>>(Y, e_nodes, OFF, EF);
  hipMemsetAsync(ACC, 0, N_NODES * CH * sizeof(float), stream);
  scatter_kernel<<<(N_INC * 8 + 255) / 256, 256, 0, stream>>>(EF, e_nodes, e_edges, ACC);

  // conv2 finalize + output linear
  out_kernel<<<(N_NODES + 255) / 256, 256, 0, stream>>>(ACC, DN, bias2, w_out, b_out, out);
}

// Round 4
// 803.062 us; speedup vs baseline: 1.0573x; 1.0573x over previous
//
#include <hip/hip_runtime.h>
#include <math.h>

#define N_NODES 50000
#define N_EDGESC 2000
#define N_INC   200000
#define SEQ     64
#define FEATN   6
#define CH      32
#define OUTF    5
#define SLOPE   0.01f

__device__ __forceinline__ float fast_rcp(float x) { return __builtin_amdgcn_rcpf(x); }
__device__ __forceinline__ float sigm(float x) { return fast_rcp(1.f + __expf(-x)); }
__device__ __forceinline__ float tanh_fast(float x) { return 1.f - 2.f * fast_rcp(1.f + __expf(2.f * x)); }
__device__ __forceinline__ float leaky(float v) { return v > 0.f ? v : SLOPE * v; }

// ---------------- GRU (one 32-lane group per node) + fused theta1 matmul ----------------
// amdgpu_waves_per_eu(2,2): rounds 1-3 showed the register allocator targets
// occupancy (VGPR 84..112) and RELOADS the 114 loop-invariant weight floats
// every t-iteration (~3x instruction bloat, 566us vs ~196us floor).
// Setting waves/EU max=2 gives the allocator a 256-VGPR budget so the whole
// weight set stays resident across the 64-step loop.
__global__ __launch_bounds__(256)
__attribute__((amdgpu_waves_per_eu(2, 2)))
void gru_theta_kernel(
    const float* __restrict__ price,
    const float* __restrict__ w_ih, const float* __restrict__ w_hh,
    const float* __restrict__ b_ih, const float* __restrict__ b_hh,
    const float* __restrict__ theta1,
    float* __restrict__ Y)
{
  __shared__ float hbuf[256];
  const int tid  = threadIdx.x;
  const int j    = tid & 31;          // hidden unit owned by this lane
  const int gb   = tid & ~31;         // group base in hbuf
  const int node = (blockIdx.x * 256 + tid) >> 5;

  // per-lane weights in registers (96 floats)
  float whr[CH], whz[CH], whn[CH];
#pragma unroll
  for (int k4 = 0; k4 < 8; ++k4) {
    float4 a = *(const float4*)(w_hh + (j       ) * CH + k4 * 4);
    float4 b = *(const float4*)(w_hh + (j + 32  ) * CH + k4 * 4);
    float4 c = *(const float4*)(w_hh + (j + 64  ) * CH + k4 * 4);
    whr[4*k4+0]=a.x; whr[4*k4+1]=a.y; whr[4*k4+2]=a.z; whr[4*k4+3]=a.w;
    whz[4*k4+0]=b.x; whz[4*k4+1]=b.y; whz[4*k4+2]=b.z; whz[4*k4+3]=b.w;
    whn[4*k4+0]=c.x; whn[4*k4+1]=c.y; whn[4*k4+2]=c.z; whn[4*k4+3]=c.w;
  }
  float wir[FEATN], wiz[FEATN], win[FEATN];
#pragma unroll
  for (int f = 0; f < FEATN; ++f) {
    wir[f] = w_ih[(j      ) * FEATN + f];
    wiz[f] = w_ih[(j + 32 ) * FEATN + f];
    win[f] = w_ih[(j + 64 ) * FEATN + f];
  }
  const float br  = b_ih[j]      + b_hh[j];
  const float bz  = b_ih[j + 32] + b_hh[j + 32];
  const float bin = b_ih[j + 64];
  const float bhn = b_hh[j + 64];

  float h = 0.f;
  const float* xp = price + node * (SEQ * FEATN);

  // software-pipelined x loads
  float2 x01 = *(const float2*)(xp);
  float2 x23 = *(const float2*)(xp + 2);
  float2 x45 = *(const float2*)(xp + 4);

  for (int t = 0; t < SEQ; ++t) {
    float gr0 = br + wir[0]*x01.x + wir[1]*x01.y;
    float gr1 =      wir[2]*x23.x + wir[3]*x23.y + wir[4]*x45.x + wir[5]*x45.y;
    float gz0 = bz + wiz[0]*x01.x + wiz[1]*x01.y;
    float gz1 =      wiz[2]*x23.x + wiz[3]*x23.y + wiz[4]*x45.x + wiz[5]*x45.y;
    float gn  = bin + win[0]*x01.x + win[1]*x01.y + win[2]*x23.x
                    + win[3]*x23.y + win[4]*x45.x + win[5]*x45.y;
    float hn0 = bhn, hn1 = 0.f;

    // prefetch next step's x (hides VMEM latency under the FMA chain)
    if (t + 1 < SEQ) {
      const float* nxt = xp + (t + 1) * FEATN;
      x01 = *(const float2*)(nxt);
      x23 = *(const float2*)(nxt + 2);
      x45 = *(const float2*)(nxt + 4);
    }

    hbuf[tid] = h;  // wave-lockstep: in-order DS pipe + may-alias keeps ordering
#pragma unroll
    for (int k4 = 0; k4 < 8; ++k4) {
      float4 hv = *(const float4*)(hbuf + gb + 4 * k4);
      gr0 += whr[4*k4+0]*hv.x; gr1 += whr[4*k4+1]*hv.y;
      gr0 += whr[4*k4+2]*hv.z; gr1 += whr[4*k4+3]*hv.w;
      gz0 += whz[4*k4+0]*hv.x; gz1 += whz[4*k4+1]*hv.y;
      gz0 += whz[4*k4+2]*hv.z; gz1 += whz[4*k4+3]*hv.w;
      hn0 += whn[4*k4+0]*hv.x; hn1 += whn[4*k4+1]*hv.y;
      hn0 += whn[4*k4+2]*hv.z; hn1 += whn[4*k4+3]*hv.w;
    }
    float r = sigm(gr0 + gr1);
    float z = sigm(gz0 + gz1);
    float n = tanh_fast(gn + r * (hn0 + hn1));
    h = (1.f - z) * n + z * h;
  }

  // epilogue: y_j = sum_k h_k * theta1[j,k]
  hbuf[tid] = h;
  float a0 = 0.f, a1 = 0.f;
#pragma unroll
  for (int k4 = 0; k4 < 8; ++k4) {
    float4 hv = *(const float4*)(hbuf + gb + 4 * k4);
    float4 tv = *(const float4*)(theta1 + j * CH + 4 * k4);
    a0 += tv.x * hv.x + tv.z * hv.z;
    a1 += tv.y * hv.y + tv.w * hv.w;
  }
  Y[node * CH + j] = a0 + a1;
}

// ---------------- degree counting ----------------
__global__ __launch_bounds__(256) void deg_kernel(
    const int* __restrict__ nodes, const int* __restrict__ edges,
    int* __restrict__ DN, int* __restrict__ DE)
{
  int i = blockIdx.x * 256 + threadIdx.x;
  if (i < N_INC) {
    atomicAdd(&DN[nodes[i]], 1);
    atomicAdd(&DE[edges[i]], 1);
  }
}

// ---------------- exclusive scan of edge degrees (single block) ----------------
__global__ __launch_bounds__(256) void scan_kernel(const int* __restrict__ DE, int* __restrict__ OFF)
{
  __shared__ int part[256];
  int t = threadIdx.x;
  int c[8]; int sum = 0;
#pragma unroll
  for (int u = 0; u < 8; ++u) {
    int idx = t * 8 + u;
    int x = (idx < N_EDGESC) ? DE[idx] : 0;
    c[u] = x; sum += x;
  }
  part[t] = sum;
  __syncthreads();
  for (int d = 1; d < 256; d <<= 1) {
    int v = (t >= d) ? part[t - d] : 0;
    __syncthreads();
    part[t] += v;
    __syncthreads();
  }
  int base = part[t] - sum;  // exclusive
#pragma unroll
  for (int u = 0; u < 8; ++u) {
    int idx = t * 8 + u;
    if (idx <= N_EDGESC) OFF[idx] = base;
    base += c[u];
  }
}

// ---------------- node->edge segmented gather-sum (one block per edge) ----------------
__global__ __launch_bounds__(128) void edge_gather_kernel(
    const float* __restrict__ X, const int* __restrict__ nodes,
    const int* __restrict__ OFF, float* __restrict__ EF)
{
  int e = blockIdx.x;
  int s = OFF[e], tE = OFF[e + 1];
  int f = threadIdx.x & 31, g = threadIdx.x >> 5;
  float acc = 0.f;
  for (int i = s + g; i < tE; i += 4)
    acc += X[nodes[i] * CH + f];
  acc += __shfl_down(acc, 32);
  __shared__ float red[32];
  if (threadIdx.x >= 64 && threadIdx.x < 96) red[f] = acc;
  __syncthreads();
  if (threadIdx.x < 32) {
    int cnt = tE - s;
    float binv = cnt > 0 ? 1.f / (float)cnt : 0.f;
    EF[e * CH + f] = (acc + red[f]) * binv;
  }
}

// ---------------- edge->node scatter (atomic) ----------------
__global__ __launch_bounds__(256) void scatter_kernel(
    const float* __restrict__ EF, const int* __restrict__ nodes,
    const int* __restrict__ edges, float* __restrict__ ACC)
{
  int gid = blockIdx.x * 256 + threadIdx.x;
  if (gid >= N_INC * 8) return;
  int i = gid >> 3, q = gid & 7;
  int e = edges[i], n = nodes[i];
  float4 v = *(const float4*)(EF + e * CH + q * 4);
  float* dst = ACC + n * CH + q * 4;
  unsafeAtomicAdd(dst + 0, v.x);
  unsafeAtomicAdd(dst + 1, v.y);
  unsafeAtomicAdd(dst + 2, v.z);
  unsafeAtomicAdd(dst + 3, v.w);
}

// ---------------- dinv+bias+leaky then theta2 matmul (8 threads per node) ----------------
__global__ __launch_bounds__(256) void fuse_theta_kernel(
    const float* __restrict__ ACC, const int* __restrict__ DN,
    const float* __restrict__ bias, const float* __restrict__ theta,
    float* __restrict__ Yout)
{
  int gid = blockIdx.x * 256 + threadIdx.x;
  if (gid >= N_NODES * 8) return;
  int n = gid >> 3, oq = gid & 7;
  int d = DN[n];
  float dinv = d > 0 ? 1.f / (float)d : 0.f;
  float v[CH];
#pragma unroll
  for (int k4 = 0; k4 < 8; ++k4) {
    float4 a = *(const float4*)(ACC + n * CH + 4 * k4);
    v[4*k4+0] = leaky(fmaf(a.x, dinv, bias[4*k4+0]));
    v[4*k4+1] = leaky(fmaf(a.y, dinv, bias[4*k4+1]));
    v[4*k4+2] = leaky(fmaf(a.z, dinv, bias[4*k4+2]));
    v[4*k4+3] = leaky(fmaf(a.w, dinv, bias[4*k4+3]));
  }
  float o[4];
#pragma unroll
  for (int r = 0; r < 4; ++r) {
    float s0 = 0.f, s1 = 0.f;
#pragma unroll
    for (int k4 = 0; k4 < 8; ++k4) {
      float4 tv = *(const float4*)(theta + (oq * 4 + r) * CH + 4 * k4);
      s0 += tv.x * v[4*k4+0] + tv.z * v[4*k4+2];
      s1 += tv.y * v[4*k4+1] + tv.w * v[4*k4+3];
    }
    o[r] = s0 + s1;
  }
  *(float4*)(Yout + n * CH + oq * 4) = make_float4(o[0], o[1], o[2], o[3]);
}

// ---------------- conv2 finalize + output linear ----------------
__global__ __launch_bounds__(256) void out_kernel(
    const float* __restrict__ ACC, const int* __restrict__ DN,
    const float* __restrict__ bias2, const float* __restrict__ w_out,
    const float* __restrict__ b_out, float* __restrict__ out)
{
  int n = blockIdx.x * 256 + threadIdx.x;
  if (n >= N_NODES) return;
  int d = DN[n];
  float dinv = d > 0 ? 1.f / (float)d : 0.f;
  float v[CH];
#pragma unroll
  for (int k4 = 0; k4 < 8; ++k4) {
    float4 a = *(const float4*)(ACC + n * CH + 4 * k4);
    v[4*k4+0] = leaky(fmaf(a.x, dinv, bias2[4*k4+0]));
    v[4*k4+1] = leaky(fmaf(a.y, dinv, bias2[4*k4+1]));
    v[4*k4+2] = leaky(fmaf(a.z, dinv, bias2[4*k4+2]));
    v[4*k4+3] = leaky(fmaf(a.w, dinv, bias2[4*k4+3]));
  }
#pragma unroll
  for (int o = 0; o < OUTF; ++o) {
    float s = b_out[o];
#pragma unroll
    for (int k = 0; k < CH; ++k) s += v[k] * w_out[o * CH + k];
    out[n * OUTF + o] = leaky(s);
  }
}

extern "C" void kernel_launch(void* const* d_in, const int* in_sizes, int n_in,
                              void* d_out, int out_size, void* d_ws, size_t ws_size,
                              hipStream_t stream)
{
  const float* price   = (const float*)d_in[0];
  const int*   e_nodes = (const int*)d_in[1];
  const int*   e_edges = (const int*)d_in[2];
  // d_in[3]=concept, d_in[4]=volumn, d_in[5]=num_edges : unused by reference math
  const float* w_ih    = (const float*)d_in[6];
  const float* w_hh    = (const float*)d_in[7];
  const float* b_ih    = (const float*)d_in[8];
  const float* b_hh    = (const float*)d_in[9];
  const float* theta1  = (const float*)d_in[10];
  const float* bias1   = (const float*)d_in[11];
  const float* theta2  = (const float*)d_in[12];
  const float* bias2   = (const float*)d_in[13];
  const float* w_out   = (const float*)d_in[14];
  const float* b_out   = (const float*)d_in[15];
  float* out = (float*)d_out;

  float* ws  = (float*)d_ws;
  float* Y   = ws;                 // [50000*32]
  float* ACC = ws + 1600000;       // [50000*32]
  float* EF  = ws + 3200000;       // [2000*32]
  int*   DN  = (int*)(ws + 3264000);  // [50000]
  int*   DE  = DN + N_NODES;          // [2000]
  int*   OFF = DE + N_EDGESC;         // [2001]

  hipMemsetAsync(DN, 0, (N_NODES + N_EDGESC + N_EDGESC + 1) * sizeof(int), stream);
  deg_kernel<<<(N_INC + 255) / 256, 256, 0, stream>>>(e_nodes, e_edges, DN, DE);
  scan_kernel<<<1, 256, 0, stream>>>(DE, OFF);

  gru_theta_kernel<<<(N_NODES * 32) / 256, 256, 0, stream>>>(
      price, w_ih, w_hh, b_ih, b_hh, theta1, Y);

  // conv1: node->edge, edge->node
  edge_gather_kernel<<<N_EDGESC, 128, 0, stream>>>(Y, e_nodes, OFF, EF);
  hipMemsetAsync(ACC, 0, N_NODES * CH * sizeof(float), stream);
  scatter_kernel<<<(N_INC * 8 + 255) / 256, 256, 0, stream>>>(EF, e_nodes, e_edges, ACC);

  // conv1 finalize + theta2
  fuse_theta_kernel<<<(N_NODES * 8 + 255) / 256, 256, 0, stream>>>(ACC, DN, bias1, theta2, Y);

  // conv2: node->edge, edge->node
  edge_gather_kernel<<<N_EDGESC, 128, 0, stream>>>(Y, e_nodes, OFF, EF);
  hipMemsetAsync(ACC, 0, N_NODES * CH * sizeof(float), stream);
  scatter_kernel<<<(N_INC * 8 + 255) / 256, 256, 0, stream>>>(EF, e_nodes, e_edges, ACC);

  // conv2 finalize + output linear
  out_kernel<<<(N_NODES + 255) / 256, 256, 0, stream>>>(ACC, DN, bias2, w_out, b_out, out);
}

// Round 5
// 506.585 us; speedup vs baseline: 1.6761x; 1.5852x over previous
//
#include <hip/hip_runtime.h>
#include <math.h>

#define N_NODES 50000
#define N_EDGESC 2000
#define N_INC   200000
#define SEQ     64
#define FEATN   6
#define CH      32
#define OUTF    5
#define SLOPE   0.01f

typedef __attribute__((ext_vector_type(8))) short bf16x8;
typedef __attribute__((ext_vector_type(4))) float f32x4;

__device__ __forceinline__ float fast_rcp(float x) { return __builtin_amdgcn_rcpf(x); }
__device__ __forceinline__ float sigm(float x) { return fast_rcp(1.f + __expf(-x)); }
__device__ __forceinline__ float tanh_fast(float x) { return 1.f - 2.f * fast_rcp(1.f + __expf(2.f * x)); }
__device__ __forceinline__ float leaky(float v) { return v > 0.f ? v : SLOPE * v; }

// bf16 round-to-nearest-even split helpers
__device__ __forceinline__ ushort f2bf(float x) {
  uint u = __float_as_uint(x);
  u = u + 0x7fffu + ((u >> 16) & 1u);
  return (ushort)(u >> 16);
}
__device__ __forceinline__ float bf2f(ushort s) {
  return __uint_as_float(((uint)s) << 16);
}

// ---------------- GRU via MFMA: one wave = 16 nodes ----------------
// Per t-step: G[96x16] = W_hh @ H via mfma_f32_16x16x32_bf16, split-bf16
// (hi+lo) on W and H (3 products, lo*lo dropped).  Input-gate part
// GI = W_ih @ x_t packed into one product's K dim: k0-5 Whi*xhi, k6-13
// Whi*xlo / Wlo*xhi, k18-19 bias hi/lo * 1.  D-layout: col=lane&15(node),
// row=4*(lane>>4)+reg(gate-row) -> h-update is lane-local.  H round-trips
// through per-wave LDS (4 ds_write_b64 + 2 ds_read_b128 per step).
__global__ __launch_bounds__(256) void gru_mfma_kernel(
    const float* __restrict__ price,
    const float* __restrict__ w_ih, const float* __restrict__ w_hh,
    const float* __restrict__ b_ih, const float* __restrict__ b_hh,
    float* __restrict__ Y)
{
  __shared__ __align__(16) ushort Hhi[4][16 * 40];  // [wave][node*40 + k], stride 40 bf16 = 80B
  __shared__ __align__(16) ushort Hlo[4][16 * 40];

  const int tid  = threadIdx.x;
  const int wid  = tid >> 6;
  const int lane = tid & 63;
  const int q    = lane >> 4;   // k-group / D-row-quad
  const int m    = lane & 15;   // node-in-wave = A-row = B/D-col
  const int node = blockIdx.x * 64 + wid * 16 + m;
  const int nodeC = node < N_NODES ? node : 0;

  ushort* Hh = &Hhi[wid][0];
  ushort* Hl = &Hlo[wid][0];

  // ---- Whh A-frags (6 tiles of 16 gate-rows), hi/lo split ----
  bf16x8 WAhi[6], WAlo[6];
#pragma unroll
  for (int tt = 0; tt < 6; ++tt) {
    const float* wr = w_hh + (tt * 16 + m) * CH + 8 * q;
    float4 v0 = *(const float4*)(wr);
    float4 v1 = *(const float4*)(wr + 4);
    float vv[8] = {v0.x, v0.y, v0.z, v0.w, v1.x, v1.y, v1.z, v1.w};
#pragma unroll
    for (int e = 0; e < 8; ++e) {
      ushort h = f2bf(vv[e]);
      WAhi[tt][e] = (short)h;
      WAlo[tt][e] = (short)f2bf(vv[e] - bf2f(h));
    }
  }

  // ---- GI A-frags: K packing per gate-row g = 16*tt + m ----
  // k0-5: hi(wih[g][0..5]) | k6,7: hi(w0),hi(w1)(x-lo terms) -> see Bx
  // k8-11: hi(w2..w5) for x-lo | k12-15: lo(w0..w3) for x-hi
  // k16,17: lo(w4),lo(w5) | k18: bias_hi | k19: bias_lo | rest 0
  bf16x8 GA[6];
#pragma unroll
  for (int tt = 0; tt < 6; ++tt) {
    int g = tt * 16 + m;
    bf16x8 a = {0, 0, 0, 0, 0, 0, 0, 0};
    if (q < 3) {
      float w[6];
#pragma unroll
      for (int f = 0; f < FEATN; ++f) w[f] = w_ih[g * FEATN + f];
      ushort wh[6]; float wl[6];
#pragma unroll
      for (int f = 0; f < FEATN; ++f) { wh[f] = f2bf(w[f]); wl[f] = w[f] - bf2f(wh[f]); }
      if (q == 0) {
        // k0..7 : [hi(w0..w5), hi(w0), hi(w1)]
#pragma unroll
        for (int f = 0; f < 6; ++f) a[f] = (short)wh[f];
        a[6] = (short)wh[0]; a[7] = (short)wh[1];
      } else if (q == 1) {
        // k8..15 : [hi(w2..w5), lo(w0..w3)]
#pragma unroll
        for (int f = 0; f < 4; ++f) a[f] = (short)wh[2 + f];
#pragma unroll
        for (int f = 0; f < 4; ++f) a[4 + f] = (short)f2bf(wl[f]);
      } else {
        // k16..23 : [lo(w4), lo(w5), bias_hi, bias_lo, 0,0,0,0]
        a[0] = (short)f2bf(wl[4]);
        a[1] = (short)f2bf(wl[5]);
        float bias = b_ih[g] + (g < 64 ? b_hh[g] : 0.f);
        ushort bh = f2bf(bias);
        a[2] = (short)bh;
        a[3] = (short)f2bf(bias - bf2f(bh));
      }
    }
    GA[tt] = a;
  }

  // b_hh for the n-gate (added before r-scaling), lane-local units
  float bhn[8];
#pragma unroll
  for (int i = 0; i < 4; ++i) {
    bhn[i]     = b_hh[64 + 4 * q + i];
    bhn[4 + i] = b_hh[80 + 4 * q + i];
  }

  // zero-init H in LDS (h0 = 0), same slots the loop writes
  {
    uint2 z; z.x = 0; z.y = 0;
    *(uint2*)(Hh + m * 40 + 4 * q) = z;
    *(uint2*)(Hh + m * 40 + 16 + 4 * q) = z;
    *(uint2*)(Hl + m * 40 + 4 * q) = z;
    *(uint2*)(Hl + m * 40 + 16 + 4 * q) = z;
  }

  float h_f32[8];
#pragma unroll
  for (int i = 0; i < 8; ++i) h_f32[i] = 0.f;

  const float* xp = price + nodeC * (SEQ * FEATN);
  float xc[6], xn[6];
  if (q < 3) {
    float2 a0 = *(const float2*)(xp);
    float2 a1 = *(const float2*)(xp + 2);
    float2 a2 = *(const float2*)(xp + 4);
    xc[0] = a0.x; xc[1] = a0.y; xc[2] = a1.x; xc[3] = a1.y; xc[4] = a2.x; xc[5] = a2.y;
  }

  const f32x4 zz = {0.f, 0.f, 0.f, 0.f};

  for (int t = 0; t < SEQ; ++t) {
    // ---- build x B-frag (hi/lo split), K matches GA packing ----
    bf16x8 Bx = {0, 0, 0, 0, 0, 0, 0, 0};
    if (q < 3) {
      ushort xh[6]; float xl[6];
#pragma unroll
      for (int f = 0; f < 6; ++f) { xh[f] = f2bf(xc[f]); xl[f] = xc[f] - bf2f(xh[f]); }
      if (q == 0) {
#pragma unroll
        for (int f = 0; f < 6; ++f) Bx[f] = (short)xh[f];
        Bx[6] = (short)f2bf(xl[0]); Bx[7] = (short)f2bf(xl[1]);
      } else if (q == 1) {
#pragma unroll
        for (int f = 0; f < 4; ++f) Bx[f] = (short)f2bf(xl[2 + f]);
#pragma unroll
        for (int f = 0; f < 4; ++f) Bx[4 + f] = (short)xh[f];
      } else {
        Bx[0] = (short)xh[4]; Bx[1] = (short)xh[5];
        Bx[2] = (short)0x3F80; Bx[3] = (short)0x3F80;  // 1.0 for bias hi/lo
      }
    }

    // prefetch next step's x
    if (t + 1 < SEQ && q < 3) {
      const float* nx = xp + (t + 1) * FEATN;
      float2 a0 = *(const float2*)(nx);
      float2 a1 = *(const float2*)(nx + 2);
      float2 a2 = *(const float2*)(nx + 4);
      xn[0] = a0.x; xn[1] = a0.y; xn[2] = a1.x; xn[3] = a1.y; xn[4] = a2.x; xn[5] = a2.y;
    }

    // ---- H B-frags from LDS ----
    bf16x8 HhF = *(bf16x8*)(Hh + m * 40 + 8 * q);
    bf16x8 HlF = *(bf16x8*)(Hl + m * 40 + 8 * q);

    // ---- MFMAs: r,z tiles merged with GI; n tiles kept separate ----
    f32x4 aRZ[4], aNh[2], aNi[2];
#pragma unroll
    for (int tt = 0; tt < 4; ++tt) {
      f32x4 a = __builtin_amdgcn_mfma_f32_16x16x32_bf16(GA[tt], Bx, zz, 0, 0, 0);
      a = __builtin_amdgcn_mfma_f32_16x16x32_bf16(WAlo[tt], HhF, a, 0, 0, 0);
      a = __builtin_amdgcn_mfma_f32_16x16x32_bf16(WAhi[tt], HlF, a, 0, 0, 0);
      a = __builtin_amdgcn_mfma_f32_16x16x32_bf16(WAhi[tt], HhF, a, 0, 0, 0);
      aRZ[tt] = a;
    }
#pragma unroll
    for (int tt = 0; tt < 2; ++tt) {
      f32x4 a = __builtin_amdgcn_mfma_f32_16x16x32_bf16(WAlo[4 + tt], HhF, zz, 0, 0, 0);
      a = __builtin_amdgcn_mfma_f32_16x16x32_bf16(WAhi[4 + tt], HlF, a, 0, 0, 0);
      a = __builtin_amdgcn_mfma_f32_16x16x32_bf16(WAhi[4 + tt], HhF, a, 0, 0, 0);
      aNh[tt] = a;
      aNi[tt] = __builtin_amdgcn_mfma_f32_16x16x32_bf16(GA[4 + tt], Bx, zz, 0, 0, 0);
    }

    // ---- gates + h-update (lane-local; unit u: s*? -> global 16*s+4q+i) ----
    ushort nhv[8], nlv[8];
#pragma unroll
    for (int s = 0; s < 2; ++s) {
#pragma unroll
      for (int i = 0; i < 4; ++i) {
        int u = s * 4 + i;
        float r  = sigm(aRZ[s][i]);
        float z  = sigm(aRZ[2 + s][i]);
        float hn = aNh[s][i] + bhn[u];
        float n  = tanh_fast(aNi[s][i] + r * hn);
        float hv = (1.f - z) * n + z * h_f32[u];
        h_f32[u] = hv;
        ushort hh = f2bf(hv);
        nhv[u] = hh;
        nlv[u] = f2bf(hv - bf2f(hh));
      }
    }

    // ---- write H back (units 4q+i at k=4q+i; 16+4q+i at k=16+4q+i) ----
    uint2 w0, w1;
    w0.x = (uint)nhv[0] | ((uint)nhv[1] << 16); w0.y = (uint)nhv[2] | ((uint)nhv[3] << 16);
    w1.x = (uint)nhv[4] | ((uint)nhv[5] << 16); w1.y = (uint)nhv[6] | ((uint)nhv[7] << 16);
    *(uint2*)(Hh + m * 40 + 4 * q) = w0;
    *(uint2*)(Hh + m * 40 + 16 + 4 * q) = w1;
    w0.x = (uint)nlv[0] | ((uint)nlv[1] << 16); w0.y = (uint)nlv[2] | ((uint)nlv[3] << 16);
    w1.x = (uint)nlv[4] | ((uint)nlv[5] << 16); w1.y = (uint)nlv[6] | ((uint)nlv[7] << 16);
    *(uint2*)(Hl + m * 40 + 4 * q) = w0;
    *(uint2*)(Hl + m * 40 + 16 + 4 * q) = w1;

    if (q < 3) {
#pragma unroll
      for (int f = 0; f < 6; ++f) xc[f] = xn[f];
    }
  }

  // ---- epilogue: coalesced Y write, h = hi + lo from LDS ----
  {
    int mm = lane >> 2, c = lane & 3;
    int onode = blockIdx.x * 64 + wid * 16 + mm;
    if (onode < N_NODES) {
      bf16x8 vh = *(bf16x8*)(Hh + mm * 40 + c * 8);
      bf16x8 vl = *(bf16x8*)(Hl + mm * 40 + c * 8);
      float o[8];
#pragma unroll
      for (int e = 0; e < 8; ++e) o[e] = bf2f((ushort)vh[e]) + bf2f((ushort)vl[e]);
      float4 o0; o0.x = o[0]; o0.y = o[1]; o0.z = o[2]; o0.w = o[3];
      float4 o1; o1.x = o[4]; o1.y = o[5]; o1.z = o[6]; o1.w = o[7];
      *(float4*)(Y + onode * CH + c * 8) = o0;
      *(float4*)(Y + onode * CH + c * 8 + 4) = o1;
    }
  }
}

// ---------------- degree counting ----------------
__global__ __launch_bounds__(256) void deg_kernel(
    const int* __restrict__ nodes, const int* __restrict__ edges,
    int* __restrict__ DN, int* __restrict__ DE)
{
  int i = blockIdx.x * 256 + threadIdx.x;
  if (i < N_INC) {
    atomicAdd(&DN[nodes[i]], 1);
    atomicAdd(&DE[edges[i]], 1);
  }
}

// ---------------- exclusive scan of edge degrees (single block) ----------------
__global__ __launch_bounds__(256) void scan_kernel(const int* __restrict__ DE, int* __restrict__ OFF)
{
  __shared__ int part[256];
  int t = threadIdx.x;
  int c[8]; int sum = 0;
#pragma unroll
  for (int u = 0; u < 8; ++u) {
    int idx = t * 8 + u;
    int x = (idx < N_EDGESC) ? DE[idx] : 0;
    c[u] = x; sum += x;
  }
  part[t] = sum;
  __syncthreads();
  for (int d = 1; d < 256; d <<= 1) {
    int v = (t >= d) ? part[t - d] : 0;
    __syncthreads();
    part[t] += v;
    __syncthreads();
  }
  int base = part[t] - sum;  // exclusive
#pragma unroll
  for (int u = 0; u < 8; ++u) {
    int idx = t * 8 + u;
    if (idx <= N_EDGESC) OFF[idx] = base;
    base += c[u];
  }
}

// ---------------- node->edge gather-sum + fused theta (2000 rows, not 50000) ----------------
// theta applied at edge level: seg_sum is linear so (seg_sum X) @ theta^T ==
// seg_sum(X @ theta^T); 25x less theta work and the GRU epilogue stays clean.
__global__ __launch_bounds__(128) void edge_gather_kernel(
    const float* __restrict__ X, const int* __restrict__ nodes,
    const int* __restrict__ OFF, const float* __restrict__ theta,
    float* __restrict__ EF)
{
  int e = blockIdx.x;
  int s = OFF[e], tE = OFF[e + 1];
  int f = threadIdx.x & 31, g = threadIdx.x >> 5;
  float acc = 0.f;
  for (int i = s + g; i < tE; i += 4)
    acc += X[nodes[i] * CH + f];
  acc += __shfl_down(acc, 32);
  __shared__ float red[32];
  __shared__ __align__(16) float e32[32];
  if (threadIdx.x >= 64 && threadIdx.x < 96) red[f] = acc;
  __syncthreads();
  if (threadIdx.x < 32) {
    int cnt = tE - s;
    float binv = cnt > 0 ? 1.f / (float)cnt : 0.f;
    e32[f] = (acc + red[f]) * binv;   // in-wave LDS: ordered by lgkmcnt
    float s0 = 0.f, s1 = 0.f;
#pragma unroll
    for (int k4 = 0; k4 < 8; ++k4) {
      float4 ev = *(float4*)(e32 + 4 * k4);
      float4 tv = *(const float4*)(theta + f * CH + 4 * k4);
      s0 += tv.x * ev.x + tv.z * ev.z;
      s1 += tv.y * ev.y + tv.w * ev.w;
    }
    EF[e * CH + f] = s0 + s1;
  }
}

// ---------------- edge->node scatter (atomic) ----------------
__global__ __launch_bounds__(256) void scatter_kernel(
    const float* __restrict__ EF, const int* __restrict__ nodes,
    const int* __restrict__ edges, float* __restrict__ ACC)
{
  int gid = blockIdx.x * 256 + threadIdx.x;
  if (gid >= N_INC * 8) return;
  int i = gid >> 3, q = gid & 7;
  int e = edges[i], n = nodes[i];
  float4 v = *(const float4*)(EF + e * CH + q * 4);
  float* dst = ACC + n * CH + q * 4;
  unsafeAtomicAdd(dst + 0, v.x);
  unsafeAtomicAdd(dst + 1, v.y);
  unsafeAtomicAdd(dst + 2, v.z);
  unsafeAtomicAdd(dst + 3, v.w);
}

// ---------------- node finalize: X = leaky(ACC*dinv + bias) ----------------
__global__ __launch_bounds__(256) void finalize_kernel(
    const float* __restrict__ ACC, const int* __restrict__ DN,
    const float* __restrict__ bias, float* __restrict__ Yout)
{
  int gid = blockIdx.x * 256 + threadIdx.x;
  if (gid >= N_NODES * 8) return;
  int n = gid >> 3, f4 = gid & 7;
  int d = DN[n];
  float dinv = d > 0 ? 1.f / (float)d : 0.f;
  float4 a = *(const float4*)(ACC + n * CH + 4 * f4);
  float4 b = *(const float4*)(bias + 4 * f4);
  float4 o;
  o.x = leaky(fmaf(a.x, dinv, b.x));
  o.y = leaky(fmaf(a.y, dinv, b.y));
  o.z = leaky(fmaf(a.z, dinv, b.z));
  o.w = leaky(fmaf(a.w, dinv, b.w));
  *(float4*)(Yout + n * CH + 4 * f4) = o;
}

// ---------------- conv2 finalize + output linear ----------------
__global__ __launch_bounds__(256) void out_kernel(
    const float* __restrict__ ACC, const int* __restrict__ DN,
    const float* __restrict__ bias2, const float* __restrict__ w_out,
    const float* __restrict__ b_out, float* __restrict__ out)
{
  int n = blockIdx.x * 256 + threadIdx.x;
  if (n >= N_NODES) return;
  int d = DN[n];
  float dinv = d > 0 ? 1.f / (float)d : 0.f;
  float v[CH];
#pragma unroll
  for (int k4 = 0; k4 < 8; ++k4) {
    float4 a = *(const float4*)(ACC + n * CH + 4 * k4);
    v[4*k4+0] = leaky(fmaf(a.x, dinv, bias2[4*k4+0]));
    v[4*k4+1] = leaky(fmaf(a.y, dinv, bias2[4*k4+1]));
    v[4*k4+2] = leaky(fmaf(a.z, dinv, bias2[4*k4+2]));
    v[4*k4+3] = leaky(fmaf(a.w, dinv, bias2[4*k4+3]));
  }
#pragma unroll
  for (int o = 0; o < OUTF; ++o) {
    float s = b_out[o];
#pragma unroll
    for (int k = 0; k < CH; ++k) s += v[k] * w_out[o * CH + k];
    out[n * OUTF + o] = leaky(s);
  }
}

extern "C" void kernel_launch(void* const* d_in, const int* in_sizes, int n_in,
                              void* d_out, int out_size, void* d_ws, size_t ws_size,
                              hipStream_t stream)
{
  const float* price   = (const float*)d_in[0];
  const int*   e_nodes = (const int*)d_in[1];
  const int*   e_edges = (const int*)d_in[2];
  // d_in[3]=concept, d_in[4]=volumn, d_in[5]=num_edges : unused by reference math
  const float* w_ih    = (const float*)d_in[6];
  const float* w_hh    = (const float*)d_in[7];
  const float* b_ih    = (const float*)d_in[8];
  const float* b_hh    = (const float*)d_in[9];
  const float* theta1  = (const float*)d_in[10];
  const float* bias1   = (const float*)d_in[11];
  const float* theta2  = (const float*)d_in[12];
  const float* bias2   = (const float*)d_in[13];
  const float* w_out   = (const float*)d_in[14];
  const float* b_out   = (const float*)d_in[15];
  float* out = (float*)d_out;

  float* ws  = (float*)d_ws;
  float* Y   = ws;                 // [50000*32]
  float* ACC = ws + 1600000;       // [50000*32]
  float* EF  = ws + 3200000;       // [2000*32]
  int*   DN  = (int*)(ws + 3264000);  // [50000]
  int*   DE  = DN + N_NODES;          // [2000]
  int*   OFF = DE + N_EDGESC;         // [2001]

  hipMemsetAsync(DN, 0, (N_NODES + N_EDGESC + N_EDGESC + 1) * sizeof(int), stream);
  deg_kernel<<<(N_INC + 255) / 256, 256, 0, stream>>>(e_nodes, e_edges, DN, DE);
  scan_kernel<<<1, 256, 0, stream>>>(DE, OFF);

  // 64 nodes per block (4 waves x 16 nodes)
  gru_mfma_kernel<<<(N_NODES + 63) / 64, 256, 0, stream>>>(
      price, w_ih, w_hh, b_ih, b_hh, Y);

  // conv1: node->edge (+theta1), edge->node
  edge_gather_kernel<<<N_EDGESC, 128, 0, stream>>>(Y, e_nodes, OFF, theta1, EF);
  hipMemsetAsync(ACC, 0, N_NODES * CH * sizeof(float), stream);
  scatter_kernel<<<(N_INC * 8 + 255) / 256, 256, 0, stream>>>(EF, e_nodes, e_edges, ACC);
  finalize_kernel<<<(N_NODES * 8 + 255) / 256, 256, 0, stream>>>(ACC, DN, bias1, Y);

  // conv2: node->edge (+theta2), edge->node
  edge_gather_kernel<<<N_EDGESC, 128, 0, stream>>>(Y, e_nodes, OFF, theta2, EF);
  hipMemsetAsync(ACC, 0, N_NODES * CH * sizeof(float), stream);
  scatter_kernel<<<(N_INC * 8 + 255) / 256, 256, 0, stream>>>(EF, e_nodes, e_edges, ACC);

  // conv2 finalize + output linear
  out_kernel<<<(N_NODES + 255) / 256, 256, 0, stream>>>(ACC, DN, bias2, w_out, b_out, out);
}

// Round 6
// 487.056 us; speedup vs baseline: 1.7433x; 1.0401x over previous
//
#include <hip/hip_runtime.h>
#include <math.h>

#define N_NODES 50000
#define N_EDGESC 2000
#define N_INC   200000
#define SEQ     64
#define FEATN   6
#define CH      32
#define OUTF    5
#define SLOPE   0.01f

typedef __attribute__((ext_vector_type(8))) short bf16x8;
typedef __attribute__((ext_vector_type(4))) float f32x4;

__device__ __forceinline__ float fast_rcp(float x) { return __builtin_amdgcn_rcpf(x); }
__device__ __forceinline__ float sigm(float x) { return fast_rcp(1.f + __expf(-x)); }
__device__ __forceinline__ float tanh_fast(float x) { return 1.f - 2.f * fast_rcp(1.f + __expf(2.f * x)); }
__device__ __forceinline__ float leaky(float v) { return v > 0.f ? v : SLOPE * v; }

// bf16 round-to-nearest-even split helpers (setup paths only)
__device__ __forceinline__ ushort f2bf(float x) {
  uint u = __float_as_uint(x);
  u = u + 0x7fffu + ((u >> 16) & 1u);
  return (ushort)(u >> 16);
}
__device__ __forceinline__ float bf2f(ushort s) {
  return __uint_as_float(((uint)s) << 16);
}
// HW packed f32->bf16 (RNE): dst.lo16 = bf16(a), dst.hi16 = bf16(b)
__device__ __forceinline__ uint pk_bf16(float a, float b) {
  uint r;
  asm("v_cvt_pk_bf16_f32 %0, %1, %2" : "=v"(r) : "v"(a), "v"(b));
  return r;
}

union BW { bf16x8 v; uint w[4]; uint2 d[2]; };

// ---------------- GRU via MFMA: one wave = 16 nodes ----------------
// Per t-step: G[96x16] = W_hh @ H via mfma_f32_16x16x32_bf16, split-bf16
// (hi+lo, lo*lo dropped).  Input-gate part packed into one product's K dim.
// D-layout: col=lane&15(node), row=4*(lane>>4)+reg -> h-update lane-local.
// Round-6 change: ALL in-loop f32->bf16 goes through v_cvt_pk_bf16_f32
// (1 instr / 2 values) + dword-level fragment builds (union BW), replacing
// scalar RNE bit-twiddling + 16-bit vector inserts (~770 -> ~210 VALU/step).
__global__ __launch_bounds__(256) void gru_mfma_kernel(
    const float* __restrict__ price,
    const float* __restrict__ w_ih, const float* __restrict__ w_hh,
    const float* __restrict__ b_ih, const float* __restrict__ b_hh,
    float* __restrict__ Y)
{
  __shared__ __align__(16) ushort Hhi[4][16 * 40];  // [wave][node*40 + k]
  __shared__ __align__(16) ushort Hlo[4][16 * 40];

  const int tid  = threadIdx.x;
  const int wid  = tid >> 6;
  const int lane = tid & 63;
  const int q    = lane >> 4;   // k-group / D-row-quad
  const int m    = lane & 15;   // node-in-wave = A-row = B/D-col
  const int node = blockIdx.x * 64 + wid * 16 + m;
  const int nodeC = node < N_NODES ? node : 0;

  ushort* Hh = &Hhi[wid][0];
  ushort* Hl = &Hlo[wid][0];

  // ---- Whh A-frags (6 tiles of 16 gate-rows), hi/lo split ----
  bf16x8 WAhi[6], WAlo[6];
#pragma unroll
  for (int tt = 0; tt < 6; ++tt) {
    const float* wr = w_hh + (tt * 16 + m) * CH + 8 * q;
    float4 v0 = *(const float4*)(wr);
    float4 v1 = *(const float4*)(wr + 4);
    float vv[8] = {v0.x, v0.y, v0.z, v0.w, v1.x, v1.y, v1.z, v1.w};
#pragma unroll
    for (int e = 0; e < 8; ++e) {
      ushort h = f2bf(vv[e]);
      WAhi[tt][e] = (short)h;
      WAlo[tt][e] = (short)f2bf(vv[e] - bf2f(h));
    }
  }

  // ---- GI A-frags: K packing per gate-row g = 16*tt + m (setup only) ----
  bf16x8 GA[6];
#pragma unroll
  for (int tt = 0; tt < 6; ++tt) {
    int g = tt * 16 + m;
    bf16x8 a = {0, 0, 0, 0, 0, 0, 0, 0};
    if (q < 3) {
      float w[6];
#pragma unroll
      for (int f = 0; f < FEATN; ++f) w[f] = w_ih[g * FEATN + f];
      ushort wh[6]; float wl[6];
#pragma unroll
      for (int f = 0; f < FEATN; ++f) { wh[f] = f2bf(w[f]); wl[f] = w[f] - bf2f(wh[f]); }
      if (q == 0) {
#pragma unroll
        for (int f = 0; f < 6; ++f) a[f] = (short)wh[f];
        a[6] = (short)wh[0]; a[7] = (short)wh[1];
      } else if (q == 1) {
#pragma unroll
        for (int f = 0; f < 4; ++f) a[f] = (short)wh[2 + f];
#pragma unroll
        for (int f = 0; f < 4; ++f) a[4 + f] = (short)f2bf(wl[f]);
      } else {
        a[0] = (short)f2bf(wl[4]);
        a[1] = (short)f2bf(wl[5]);
        float bias = b_ih[g] + (g < 64 ? b_hh[g] : 0.f);
        ushort bh = f2bf(bias);
        a[2] = (short)bh;
        a[3] = (short)f2bf(bias - bf2f(bh));
      }
    }
    GA[tt] = a;
  }

  // b_hh for the n-gate, lane-local units
  float bhn[8];
#pragma unroll
  for (int i = 0; i < 4; ++i) {
    bhn[i]     = b_hh[64 + 4 * q + i];
    bhn[4 + i] = b_hh[80 + 4 * q + i];
  }

  // zero-init H in LDS (h0 = 0)
  {
    uint2 z; z.x = 0; z.y = 0;
    *(uint2*)(Hh + m * 40 + 4 * q) = z;
    *(uint2*)(Hh + m * 40 + 16 + 4 * q) = z;
    *(uint2*)(Hl + m * 40 + 4 * q) = z;
    *(uint2*)(Hl + m * 40 + 16 + 4 * q) = z;
  }

  float h_f32[8];
#pragma unroll
  for (int i = 0; i < 8; ++i) h_f32[i] = 0.f;

  const float* xp = price + nodeC * (SEQ * FEATN);
  float xc[6], xn[6];
  if (q < 3) {
    float2 a0 = *(const float2*)(xp);
    float2 a1 = *(const float2*)(xp + 2);
    float2 a2 = *(const float2*)(xp + 4);
    xc[0] = a0.x; xc[1] = a0.y; xc[2] = a1.x; xc[3] = a1.y; xc[4] = a2.x; xc[5] = a2.y;
  }

  const f32x4 zz = {0.f, 0.f, 0.f, 0.f};

  for (int t = 0; t < SEQ; ++t) {
    // ---- build x B-frag via packed cvt (hi/lo split) ----
    BW bx; bx.w[0] = 0; bx.w[1] = 0; bx.w[2] = 0; bx.w[3] = 0;
    if (q < 3) {
      uint p01 = pk_bf16(xc[0], xc[1]);
      uint p23 = pk_bf16(xc[2], xc[3]);
      uint p45 = pk_bf16(xc[4], xc[5]);
      float l0 = xc[0] - __uint_as_float(p01 << 16);
      float l1 = xc[1] - __uint_as_float(p01 & 0xFFFF0000u);
      float l2 = xc[2] - __uint_as_float(p23 << 16);
      float l3 = xc[3] - __uint_as_float(p23 & 0xFFFF0000u);
      float l4 = xc[4] - __uint_as_float(p45 << 16);
      float l5 = xc[5] - __uint_as_float(p45 & 0xFFFF0000u);
      if (q == 0) {
        bx.w[0] = p01; bx.w[1] = p23; bx.w[2] = p45;
        bx.w[3] = pk_bf16(l0, l1);
      } else if (q == 1) {
        bx.w[0] = pk_bf16(l2, l3); bx.w[1] = pk_bf16(l4, l5);
        bx.w[2] = p01; bx.w[3] = p23;
      } else {
        bx.w[0] = p45; bx.w[1] = 0x3F803F80u;  // bias slots: 1.0, 1.0
      }
    }
    bf16x8 Bx = bx.v;

    // prefetch next step's x
    if (t + 1 < SEQ && q < 3) {
      const float* nx = xp + (t + 1) * FEATN;
      float2 a0 = *(const float2*)(nx);
      float2 a1 = *(const float2*)(nx + 2);
      float2 a2 = *(const float2*)(nx + 4);
      xn[0] = a0.x; xn[1] = a0.y; xn[2] = a1.x; xn[3] = a1.y; xn[4] = a2.x; xn[5] = a2.y;
    }

    // ---- H B-frags from LDS ----
    bf16x8 HhF = *(bf16x8*)(Hh + m * 40 + 8 * q);
    bf16x8 HlF = *(bf16x8*)(Hl + m * 40 + 8 * q);

    // ---- MFMAs ----
    f32x4 aRZ[4], aNh[2], aNi[2];
#pragma unroll
    for (int tt = 0; tt < 4; ++tt) {
      f32x4 a = __builtin_amdgcn_mfma_f32_16x16x32_bf16(GA[tt], Bx, zz, 0, 0, 0);
      a = __builtin_amdgcn_mfma_f32_16x16x32_bf16(WAlo[tt], HhF, a, 0, 0, 0);
      a = __builtin_amdgcn_mfma_f32_16x16x32_bf16(WAhi[tt], HlF, a, 0, 0, 0);
      a = __builtin_amdgcn_mfma_f32_16x16x32_bf16(WAhi[tt], HhF, a, 0, 0, 0);
      aRZ[tt] = a;
    }
#pragma unroll
    for (int tt = 0; tt < 2; ++tt) {
      f32x4 a = __builtin_amdgcn_mfma_f32_16x16x32_bf16(WAlo[4 + tt], HhF, zz, 0, 0, 0);
      a = __builtin_amdgcn_mfma_f32_16x16x32_bf16(WAhi[4 + tt], HlF, a, 0, 0, 0);
      a = __builtin_amdgcn_mfma_f32_16x16x32_bf16(WAhi[4 + tt], HhF, a, 0, 0, 0);
      aNh[tt] = a;
      aNi[tt] = __builtin_amdgcn_mfma_f32_16x16x32_bf16(GA[4 + tt], Bx, zz, 0, 0, 0);
    }

    // ---- gates + h-update (lane-local) ----
    float hv[8];
#pragma unroll
    for (int s = 0; s < 2; ++s) {
#pragma unroll
      for (int i = 0; i < 4; ++i) {
        int u = s * 4 + i;
        float r  = sigm(aRZ[s][i]);
        float z  = sigm(aRZ[2 + s][i]);
        float n  = tanh_fast(aNi[s][i] + r * (aNh[s][i] + bhn[u]));
        float h2 = n + z * (h_f32[u] - n);
        h_f32[u] = h2;
        hv[u] = h2;
      }
    }

    // ---- packed H writeback (hi + lo), dword stores ----
    uint ph0 = pk_bf16(hv[0], hv[1]);
    uint ph1 = pk_bf16(hv[2], hv[3]);
    uint ph2 = pk_bf16(hv[4], hv[5]);
    uint ph3 = pk_bf16(hv[6], hv[7]);
    float l0 = hv[0] - __uint_as_float(ph0 << 16);
    float l1 = hv[1] - __uint_as_float(ph0 & 0xFFFF0000u);
    float l2 = hv[2] - __uint_as_float(ph1 << 16);
    float l3 = hv[3] - __uint_as_float(ph1 & 0xFFFF0000u);
    float l4 = hv[4] - __uint_as_float(ph2 << 16);
    float l5 = hv[5] - __uint_as_float(ph2 & 0xFFFF0000u);
    float l6 = hv[6] - __uint_as_float(ph3 << 16);
    float l7 = hv[7] - __uint_as_float(ph3 & 0xFFFF0000u);
    uint2 wa, wb;
    wa.x = ph0; wa.y = ph1; wb.x = ph2; wb.y = ph3;
    *(uint2*)(Hh + m * 40 + 4 * q) = wa;
    *(uint2*)(Hh + m * 40 + 16 + 4 * q) = wb;
    wa.x = pk_bf16(l0, l1); wa.y = pk_bf16(l2, l3);
    wb.x = pk_bf16(l4, l5); wb.y = pk_bf16(l6, l7);
    *(uint2*)(Hl + m * 40 + 4 * q) = wa;
    *(uint2*)(Hl + m * 40 + 16 + 4 * q) = wb;

    if (q < 3) {
#pragma unroll
      for (int f = 0; f < 6; ++f) xc[f] = xn[f];
    }
  }

  // ---- epilogue: coalesced Y write, h = hi + lo from LDS ----
  {
    int mm = lane >> 2, c = lane & 3;
    int onode = blockIdx.x * 64 + wid * 16 + mm;
    if (onode < N_NODES) {
      bf16x8 vh = *(bf16x8*)(Hh + mm * 40 + c * 8);
      bf16x8 vl = *(bf16x8*)(Hl + mm * 40 + c * 8);
      float o[8];
#pragma unroll
      for (int e = 0; e < 8; ++e) o[e] = bf2f((ushort)vh[e]) + bf2f((ushort)vl[e]);
      float4 o0; o0.x = o[0]; o0.y = o[1]; o0.z = o[2]; o0.w = o[3];
      float4 o1; o1.x = o[4]; o1.y = o[5]; o1.z = o[6]; o1.w = o[7];
      *(float4*)(Y + onode * CH + c * 8) = o0;
      *(float4*)(Y + onode * CH + c * 8 + 4) = o1;
    }
  }
}

// ---------------- degree counting ----------------
__global__ __launch_bounds__(256) void deg_kernel(
    const int* __restrict__ nodes, const int* __restrict__ edges,
    int* __restrict__ DN, int* __restrict__ DE)
{
  int i = blockIdx.x * 256 + threadIdx.x;
  if (i < N_INC) {
    atomicAdd(&DN[nodes[i]], 1);
    atomicAdd(&DE[edges[i]], 1);
  }
}

// ---------------- exclusive scan of edge degrees (single block) ----------------
__global__ __launch_bounds__(256) void scan_kernel(const int* __restrict__ DE, int* __restrict__ OFF)
{
  __shared__ int part[256];
  int t = threadIdx.x;
  int c[8]; int sum = 0;
#pragma unroll
  for (int u = 0; u < 8; ++u) {
    int idx = t * 8 + u;
    int x = (idx < N_EDGESC) ? DE[idx] : 0;
    c[u] = x; sum += x;
  }
  part[t] = sum;
  __syncthreads();
  for (int d = 1; d < 256; d <<= 1) {
    int v = (t >= d) ? part[t - d] : 0;
    __syncthreads();
    part[t] += v;
    __syncthreads();
  }
  int base = part[t] - sum;  // exclusive
#pragma unroll
  for (int u = 0; u < 8; ++u) {
    int idx = t * 8 + u;
    if (idx <= N_EDGESC) OFF[idx] = base;
    base += c[u];
  }
}

// ---------------- node->edge gather-sum + fused theta ----------------
__global__ __launch_bounds__(128) void edge_gather_kernel(
    const float* __restrict__ X, const int* __restrict__ nodes,
    const int* __restrict__ OFF, const float* __restrict__ theta,
    float* __restrict__ EF)
{
  int e = blockIdx.x;
  int s = OFF[e], tE = OFF[e + 1];
  int f = threadIdx.x & 31, g = threadIdx.x >> 5;
  float acc = 0.f;
  for (int i = s + g; i < tE; i += 4)
    acc += X[nodes[i] * CH + f];
  acc += __shfl_down(acc, 32);
  __shared__ float red[32];
  __shared__ __align__(16) float e32[32];
  if (threadIdx.x >= 64 && threadIdx.x < 96) red[f] = acc;
  __syncthreads();
  if (threadIdx.x < 32) {
    int cnt = tE - s;
    float binv = cnt > 0 ? 1.f / (float)cnt : 0.f;
    e32[f] = (acc + red[f]) * binv;
    float s0 = 0.f, s1 = 0.f;
#pragma unroll
    for (int k4 = 0; k4 < 8; ++k4) {
      float4 ev = *(float4*)(e32 + 4 * k4);
      float4 tv = *(const float4*)(theta + f * CH + 4 * k4);
      s0 += tv.x * ev.x + tv.z * ev.z;
      s1 += tv.y * ev.y + tv.w * ev.w;
    }
    EF[e * CH + f] = s0 + s1;
  }
}

// ---------------- edge->node scatter (atomic) ----------------
__global__ __launch_bounds__(256) void scatter_kernel(
    const float* __restrict__ EF, const int* __restrict__ nodes,
    const int* __restrict__ edges, float* __restrict__ ACC)
{
  int gid = blockIdx.x * 256 + threadIdx.x;
  if (gid >= N_INC * 8) return;
  int i = gid >> 3, q = gid & 7;
  int e = edges[i], n = nodes[i];
  float4 v = *(const float4*)(EF + e * CH + q * 4);
  float* dst = ACC + n * CH + q * 4;
  unsafeAtomicAdd(dst + 0, v.x);
  unsafeAtomicAdd(dst + 1, v.y);
  unsafeAtomicAdd(dst + 2, v.z);
  unsafeAtomicAdd(dst + 3, v.w);
}

// ---------------- node finalize: X = leaky(ACC*dinv + bias) ----------------
__global__ __launch_bounds__(256) void finalize_kernel(
    const float* __restrict__ ACC, const int* __restrict__ DN,
    const float* __restrict__ bias, float* __restrict__ Yout)
{
  int gid = blockIdx.x * 256 + threadIdx.x;
  if (gid >= N_NODES * 8) return;
  int n = gid >> 3, f4 = gid & 7;
  int d = DN[n];
  float dinv = d > 0 ? 1.f / (float)d : 0.f;
  float4 a = *(const float4*)(ACC + n * CH + 4 * f4);
  float4 b = *(const float4*)(bias + 4 * f4);
  float4 o;
  o.x = leaky(fmaf(a.x, dinv, b.x));
  o.y = leaky(fmaf(a.y, dinv, b.y));
  o.z = leaky(fmaf(a.z, dinv, b.z));
  o.w = leaky(fmaf(a.w, dinv, b.w));
  *(float4*)(Yout + n * CH + 4 * f4) = o;
}

// ---------------- conv2 finalize + output linear ----------------
__global__ __launch_bounds__(256) void out_kernel(
    const float* __restrict__ ACC, const int* __restrict__ DN,
    const float* __restrict__ bias2, const float* __restrict__ w_out,
    const float* __restrict__ b_out, float* __restrict__ out)
{
  int n = blockIdx.x * 256 + threadIdx.x;
  if (n >= N_NODES) return;
  int d = DN[n];
  float dinv = d > 0 ? 1.f / (float)d : 0.f;
  float v[CH];
#pragma unroll
  for (int k4 = 0; k4 < 8; ++k4) {
    float4 a = *(const float4*)(ACC + n * CH + 4 * k4);
    v[4*k4+0] = leaky(fmaf(a.x, dinv, bias2[4*k4+0]));
    v[4*k4+1] = leaky(fmaf(a.y, dinv, bias2[4*k4+1]));
    v[4*k4+2] = leaky(fmaf(a.z, dinv, bias2[4*k4+2]));
    v[4*k4+3] = leaky(fmaf(a.w, dinv, bias2[4*k4+3]));
  }
#pragma unroll
  for (int o = 0; o < OUTF; ++o) {
    float s = b_out[o];
#pragma unroll
    for (int k = 0; k < CH; ++k) s += v[k] * w_out[o * CH + k];
    out[n * OUTF + o] = leaky(s);
  }
}

extern "C" void kernel_launch(void* const* d_in, const int* in_sizes, int n_in,
                              void* d_out, int out_size, void* d_ws, size_t ws_size,
                              hipStream_t stream)
{
  const float* price   = (const float*)d_in[0];
  const int*   e_nodes = (const int*)d_in[1];
  const int*   e_edges = (const int*)d_in[2];
  const float* w_ih    = (const float*)d_in[6];
  const float* w_hh    = (const float*)d_in[7];
  const float* b_ih    = (const float*)d_in[8];
  const float* b_hh    = (const float*)d_in[9];
  const float* theta1  = (const float*)d_in[10];
  const float* bias1   = (const float*)d_in[11];
  const float* theta2  = (const float*)d_in[12];
  const float* bias2   = (const float*)d_in[13];
  const float* w_out   = (const float*)d_in[14];
  const float* b_out   = (const float*)d_in[15];
  float* out = (float*)d_out;

  float* ws  = (float*)d_ws;
  float* Y   = ws;                 // [50000*32]
  float* ACC = ws + 1600000;       // [50000*32]
  float* EF  = ws + 3200000;       // [2000*32]
  int*   DN  = (int*)(ws + 3264000);  // [50000]
  int*   DE  = DN + N_NODES;          // [2000]
  int*   OFF = DE + N_EDGESC;         // [2001]

  hipMemsetAsync(DN, 0, (N_NODES + N_EDGESC + N_EDGESC + 1) * sizeof(int), stream);
  deg_kernel<<<(N_INC + 255) / 256, 256, 0, stream>>>(e_nodes, e_edges, DN, DE);
  scan_kernel<<<1, 256, 0, stream>>>(DE, OFF);

  // 64 nodes per block (4 waves x 16 nodes)
  gru_mfma_kernel<<<(N_NODES + 63) / 64, 256, 0, stream>>>(
      price, w_ih, w_hh, b_ih, b_hh, Y);

  // conv1: node->edge (+theta1), edge->node
  edge_gather_kernel<<<N_EDGESC, 128, 0, stream>>>(Y, e_nodes, OFF, theta1, EF);
  hipMemsetAsync(ACC, 0, N_NODES * CH * sizeof(float), stream);
  scatter_kernel<<<(N_INC * 8 + 255) / 256, 256, 0, stream>>>(EF, e_nodes, e_edges, ACC);
  finalize_kernel<<<(N_NODES * 8 + 255) / 256, 256, 0, stream>>>(ACC, DN, bias1, Y);

  // conv2: node->edge (+theta2), edge->node
  edge_gather_kernel<<<N_EDGESC, 128, 0, stream>>>(Y, e_nodes, OFF, theta2, EF);
  hipMemsetAsync(ACC, 0, N_NODES * CH * sizeof(float), stream);
  scatter_kernel<<<(N_INC * 8 + 255) / 256, 256, 0, stream>>>(EF, e_nodes, e_edges, ACC);

  // conv2 finalize + output linear
  out_kernel<<<(N_NODES + 255) / 256, 256, 0, stream>>>(ACC, DN, bias2, w_out, b_out, out);
}

// Round 7
// 380.224 us; speedup vs baseline: 2.2332x; 1.2810x over previous
//
#include <hip/hip_runtime.h>
#include <math.h>

#define N_NODES 50000
#define N_EDGESC 2000
#define N_INC   200000
#define SEQ     64
#define FEATN   6
#define CH      32
#define OUTF    5
#define SLOPE   0.01f

typedef __attribute__((ext_vector_type(8))) short bf16x8;
typedef __attribute__((ext_vector_type(4))) float f32x4;

__device__ __forceinline__ float fast_rcp(float x) { return __builtin_amdgcn_rcpf(x); }
__device__ __forceinline__ float sigm(float x) { return fast_rcp(1.f + __expf(-x)); }
__device__ __forceinline__ float tanh_fast(float x) { return 1.f - 2.f * fast_rcp(1.f + __expf(2.f * x)); }
__device__ __forceinline__ float leaky(float v) { return v > 0.f ? v : SLOPE * v; }

__device__ __forceinline__ ushort f2bf(float x) {
  uint u = __float_as_uint(x);
  u = u + 0x7fffu + ((u >> 16) & 1u);
  return (ushort)(u >> 16);
}
__device__ __forceinline__ float bf2f(ushort s) {
  return __uint_as_float(((uint)s) << 16);
}
__device__ __forceinline__ uint pk_bf16(float a, float b) {
  uint r;
  asm("v_cvt_pk_bf16_f32 %0, %1, %2" : "=v"(r) : "v"(a), "v"(b));
  return r;
}

union BW { bf16x8 v; uint w[4]; uint2 d[2]; };

// ---------------- GRU via MFMA (FROZEN from round 6 for attribution) ----------------
__global__ __launch_bounds__(256) void gru_mfma_kernel(
    const float* __restrict__ price,
    const float* __restrict__ w_ih, const float* __restrict__ w_hh,
    const float* __restrict__ b_ih, const float* __restrict__ b_hh,
    float* __restrict__ Y)
{
  __shared__ __align__(16) ushort Hhi[4][16 * 40];
  __shared__ __align__(16) ushort Hlo[4][16 * 40];

  const int tid  = threadIdx.x;
  const int wid  = tid >> 6;
  const int lane = tid & 63;
  const int q    = lane >> 4;
  const int m    = lane & 15;
  const int node = blockIdx.x * 64 + wid * 16 + m;
  const int nodeC = node < N_NODES ? node : 0;

  ushort* Hh = &Hhi[wid][0];
  ushort* Hl = &Hlo[wid][0];

  bf16x8 WAhi[6], WAlo[6];
#pragma unroll
  for (int tt = 0; tt < 6; ++tt) {
    const float* wr = w_hh + (tt * 16 + m) * CH + 8 * q;
    float4 v0 = *(const float4*)(wr);
    float4 v1 = *(const float4*)(wr + 4);
    float vv[8] = {v0.x, v0.y, v0.z, v0.w, v1.x, v1.y, v1.z, v1.w};
#pragma unroll
    for (int e = 0; e < 8; ++e) {
      ushort h = f2bf(vv[e]);
      WAhi[tt][e] = (short)h;
      WAlo[tt][e] = (short)f2bf(vv[e] - bf2f(h));
    }
  }

  bf16x8 GA[6];
#pragma unroll
  for (int tt = 0; tt < 6; ++tt) {
    int g = tt * 16 + m;
    bf16x8 a = {0, 0, 0, 0, 0, 0, 0, 0};
    if (q < 3) {
      float w[6];
#pragma unroll
      for (int f = 0; f < FEATN; ++f) w[f] = w_ih[g * FEATN + f];
      ushort wh[6]; float wl[6];
#pragma unroll
      for (int f = 0; f < FEATN; ++f) { wh[f] = f2bf(w[f]); wl[f] = w[f] - bf2f(wh[f]); }
      if (q == 0) {
#pragma unroll
        for (int f = 0; f < 6; ++f) a[f] = (short)wh[f];
        a[6] = (short)wh[0]; a[7] = (short)wh[1];
      } else if (q == 1) {
#pragma unroll
        for (int f = 0; f < 4; ++f) a[f] = (short)wh[2 + f];
#pragma unroll
        for (int f = 0; f < 4; ++f) a[4 + f] = (short)f2bf(wl[f]);
      } else {
        a[0] = (short)f2bf(wl[4]);
        a[1] = (short)f2bf(wl[5]);
        float bias = b_ih[g] + (g < 64 ? b_hh[g] : 0.f);
        ushort bh = f2bf(bias);
        a[2] = (short)bh;
        a[3] = (short)f2bf(bias - bf2f(bh));
      }
    }
    GA[tt] = a;
  }

  float bhn[8];
#pragma unroll
  for (int i = 0; i < 4; ++i) {
    bhn[i]     = b_hh[64 + 4 * q + i];
    bhn[4 + i] = b_hh[80 + 4 * q + i];
  }

  {
    uint2 z; z.x = 0; z.y = 0;
    *(uint2*)(Hh + m * 40 + 4 * q) = z;
    *(uint2*)(Hh + m * 40 + 16 + 4 * q) = z;
    *(uint2*)(Hl + m * 40 + 4 * q) = z;
    *(uint2*)(Hl + m * 40 + 16 + 4 * q) = z;
  }

  float h_f32[8];
#pragma unroll
  for (int i = 0; i < 8; ++i) h_f32[i] = 0.f;

  const float* xp = price + nodeC * (SEQ * FEATN);
  float xc[6], xn[6];
  if (q < 3) {
    float2 a0 = *(const float2*)(xp);
    float2 a1 = *(const float2*)(xp + 2);
    float2 a2 = *(const float2*)(xp + 4);
    xc[0] = a0.x; xc[1] = a0.y; xc[2] = a1.x; xc[3] = a1.y; xc[4] = a2.x; xc[5] = a2.y;
  }

  const f32x4 zz = {0.f, 0.f, 0.f, 0.f};

  for (int t = 0; t < SEQ; ++t) {
    BW bx; bx.w[0] = 0; bx.w[1] = 0; bx.w[2] = 0; bx.w[3] = 0;
    if (q < 3) {
      uint p01 = pk_bf16(xc[0], xc[1]);
      uint p23 = pk_bf16(xc[2], xc[3]);
      uint p45 = pk_bf16(xc[4], xc[5]);
      float l0 = xc[0] - __uint_as_float(p01 << 16);
      float l1 = xc[1] - __uint_as_float(p01 & 0xFFFF0000u);
      float l2 = xc[2] - __uint_as_float(p23 << 16);
      float l3 = xc[3] - __uint_as_float(p23 & 0xFFFF0000u);
      float l4 = xc[4] - __uint_as_float(p45 << 16);
      float l5 = xc[5] - __uint_as_float(p45 & 0xFFFF0000u);
      if (q == 0) {
        bx.w[0] = p01; bx.w[1] = p23; bx.w[2] = p45;
        bx.w[3] = pk_bf16(l0, l1);
      } else if (q == 1) {
        bx.w[0] = pk_bf16(l2, l3); bx.w[1] = pk_bf16(l4, l5);
        bx.w[2] = p01; bx.w[3] = p23;
      } else {
        bx.w[0] = p45; bx.w[1] = 0x3F803F80u;
      }
    }
    bf16x8 Bx = bx.v;

    if (t + 1 < SEQ && q < 3) {
      const float* nx = xp + (t + 1) * FEATN;
      float2 a0 = *(const float2*)(nx);
      float2 a1 = *(const float2*)(nx + 2);
      float2 a2 = *(const float2*)(nx + 4);
      xn[0] = a0.x; xn[1] = a0.y; xn[2] = a1.x; xn[3] = a1.y; xn[4] = a2.x; xn[5] = a2.y;
    }

    bf16x8 HhF = *(bf16x8*)(Hh + m * 40 + 8 * q);
    bf16x8 HlF = *(bf16x8*)(Hl + m * 40 + 8 * q);

    f32x4 aRZ[4], aNh[2], aNi[2];
#pragma unroll
    for (int tt = 0; tt < 4; ++tt) {
      f32x4 a = __builtin_amdgcn_mfma_f32_16x16x32_bf16(GA[tt], Bx, zz, 0, 0, 0);
      a = __builtin_amdgcn_mfma_f32_16x16x32_bf16(WAlo[tt], HhF, a, 0, 0, 0);
      a = __builtin_amdgcn_mfma_f32_16x16x32_bf16(WAhi[tt], HlF, a, 0, 0, 0);
      a = __builtin_amdgcn_mfma_f32_16x16x32_bf16(WAhi[tt], HhF, a, 0, 0, 0);
      aRZ[tt] = a;
    }
#pragma unroll
    for (int tt = 0; tt < 2; ++tt) {
      f32x4 a = __builtin_amdgcn_mfma_f32_16x16x32_bf16(WAlo[4 + tt], HhF, zz, 0, 0, 0);
      a = __builtin_amdgcn_mfma_f32_16x16x32_bf16(WAhi[4 + tt], HlF, a, 0, 0, 0);
      a = __builtin_amdgcn_mfma_f32_16x16x32_bf16(WAhi[4 + tt], HhF, a, 0, 0, 0);
      aNh[tt] = a;
      aNi[tt] = __builtin_amdgcn_mfma_f32_16x16x32_bf16(GA[4 + tt], Bx, zz, 0, 0, 0);
    }

    float hv[8];
#pragma unroll
    for (int s = 0; s < 2; ++s) {
#pragma unroll
      for (int i = 0; i < 4; ++i) {
        int u = s * 4 + i;
        float r  = sigm(aRZ[s][i]);
        float z  = sigm(aRZ[2 + s][i]);
        float n  = tanh_fast(aNi[s][i] + r * (aNh[s][i] + bhn[u]));
        float h2 = n + z * (h_f32[u] - n);
        h_f32[u] = h2;
        hv[u] = h2;
      }
    }

    uint ph0 = pk_bf16(hv[0], hv[1]);
    uint ph1 = pk_bf16(hv[2], hv[3]);
    uint ph2 = pk_bf16(hv[4], hv[5]);
    uint ph3 = pk_bf16(hv[6], hv[7]);
    float l0 = hv[0] - __uint_as_float(ph0 << 16);
    float l1 = hv[1] - __uint_as_float(ph0 & 0xFFFF0000u);
    float l2 = hv[2] - __uint_as_float(ph1 << 16);
    float l3 = hv[3] - __uint_as_float(ph1 & 0xFFFF0000u);
    float l4 = hv[4] - __uint_as_float(ph2 << 16);
    float l5 = hv[5] - __uint_as_float(ph2 & 0xFFFF0000u);
    float l6 = hv[6] - __uint_as_float(ph3 << 16);
    float l7 = hv[7] - __uint_as_float(ph3 & 0xFFFF0000u);
    uint2 wa, wb;
    wa.x = ph0; wa.y = ph1; wb.x = ph2; wb.y = ph3;
    *(uint2*)(Hh + m * 40 + 4 * q) = wa;
    *(uint2*)(Hh + m * 40 + 16 + 4 * q) = wb;
    wa.x = pk_bf16(l0, l1); wa.y = pk_bf16(l2, l3);
    wb.x = pk_bf16(l4, l5); wb.y = pk_bf16(l6, l7);
    *(uint2*)(Hl + m * 40 + 4 * q) = wa;
    *(uint2*)(Hl + m * 40 + 16 + 4 * q) = wb;

    if (q < 3) {
#pragma unroll
      for (int f = 0; f < 6; ++f) xc[f] = xn[f];
    }
  }

  {
    int mm = lane >> 2, c = lane & 3;
    int onode = blockIdx.x * 64 + wid * 16 + mm;
    if (onode < N_NODES) {
      bf16x8 vh = *(bf16x8*)(Hh + mm * 40 + c * 8);
      bf16x8 vl = *(bf16x8*)(Hl + mm * 40 + c * 8);
      float o[8];
#pragma unroll
      for (int e = 0; e < 8; ++e) o[e] = bf2f((ushort)vh[e]) + bf2f((ushort)vl[e]);
      float4 o0; o0.x = o[0]; o0.y = o[1]; o0.z = o[2]; o0.w = o[3];
      float4 o1; o1.x = o[4]; o1.y = o[5]; o1.z = o[6]; o1.w = o[7];
      *(float4*)(Y + onode * CH + c * 8) = o0;
      *(float4*)(Y + onode * CH + c * 8 + 4) = o1;
    }
  }
}

// ---------------- degree counting ----------------
__global__ __launch_bounds__(256) void deg_kernel(
    const int* __restrict__ nodes, const int* __restrict__ edges,
    int* __restrict__ DN, int* __restrict__ DE)
{
  int i = blockIdx.x * 256 + threadIdx.x;
  if (i < N_INC) {
    atomicAdd(&DN[nodes[i]], 1);
    atomicAdd(&DE[edges[i]], 1);
  }
}

// ---------------- exclusive scan of edge degrees (single block, 2000) ----------------
__global__ __launch_bounds__(256) void scan_kernel(const int* __restrict__ DE, int* __restrict__ OFF)
{
  __shared__ int part[256];
  int t = threadIdx.x;
  int c[8]; int sum = 0;
#pragma unroll
  for (int u = 0; u < 8; ++u) {
    int idx = t * 8 + u;
    int x = (idx < N_EDGESC) ? DE[idx] : 0;
    c[u] = x; sum += x;
  }
  part[t] = sum;
  __syncthreads();
  for (int d = 1; d < 256; d <<= 1) {
    int v = (t >= d) ? part[t - d] : 0;
    __syncthreads();
    part[t] += v;
    __syncthreads();
  }
  int base = part[t] - sum;
#pragma unroll
  for (int u = 0; u < 8; ++u) {
    int idx = t * 8 + u;
    if (idx <= N_EDGESC) OFF[idx] = base;
    base += c[u];
  }
}

// ---------------- exclusive scan of node degrees (single block 1024, 50000) ----------------
#define NPER 49  // 1024*49 >= 50000
__global__ __launch_bounds__(1024) void nscan_kernel(
    const int* __restrict__ DN, int* __restrict__ NOFF, int* __restrict__ CUR)
{
  __shared__ int part[1024];
  int t = threadIdx.x;
  int cl[NPER]; int sum = 0;
  int base_i = t * NPER;
#pragma unroll
  for (int u = 0; u < NPER; ++u) {
    int idx = base_i + u;
    int x = (idx < N_NODES) ? DN[idx] : 0;
    cl[u] = x; sum += x;
  }
  part[t] = sum;
  __syncthreads();
  for (int d = 1; d < 1024; d <<= 1) {
    int v = (t >= d) ? part[t - d] : 0;
    __syncthreads();
    part[t] += v;
    __syncthreads();
  }
  int run = part[t] - sum;  // exclusive
#pragma unroll
  for (int u = 0; u < NPER; ++u) {
    int idx = base_i + u;
    if (idx < N_NODES) { NOFF[idx] = run; CUR[idx] = run; }
    run += cl[u];
  }
  if (t == 1023) NOFF[N_NODES] = run;
}

// ---------------- bucket incidences by node: INCN[pos] = edge ----------------
__global__ __launch_bounds__(256) void bucket_kernel(
    const int* __restrict__ nodes, const int* __restrict__ edges,
    int* __restrict__ CUR, int* __restrict__ INCN)
{
  int i = blockIdx.x * 256 + threadIdx.x;
  if (i < N_INC) {
    int p = atomicAdd(&CUR[nodes[i]], 1);
    INCN[p] = edges[i];
  }
}

// ---------------- node->edge gather-sum + fused theta (256 thr, 2-way ILP) ----------------
__global__ __launch_bounds__(256) void edge_gather_kernel(
    const float* __restrict__ X, const int* __restrict__ nodes,
    const int* __restrict__ OFF, const float* __restrict__ theta,
    float* __restrict__ EF)
{
  int e = blockIdx.x;
  int s = OFF[e], tE = OFF[e + 1];
  int f = threadIdx.x & 31, g = threadIdx.x >> 5;  // 8 row-groups
  float a0 = 0.f, a1 = 0.f;
  for (int i = s + g; i < tE; i += 16) {
    a0 += X[nodes[i] * CH + f];
    if (i + 8 < tE) a1 += X[nodes[i + 8] * CH + f];
  }
  __shared__ float red[8][33];
  __shared__ __align__(16) float e32[32];
  red[g][f] = a0 + a1;
  __syncthreads();
  if (threadIdx.x < 32) {
    float acc = 0.f;
#pragma unroll
    for (int r = 0; r < 8; ++r) acc += red[r][f];
    int cnt = tE - s;
    float binv = cnt > 0 ? 1.f / (float)cnt : 0.f;
    e32[f] = acc * binv;           // in-wave LDS, ordered by lgkmcnt
    float s0 = 0.f, s1 = 0.f;
#pragma unroll
    for (int k4 = 0; k4 < 8; ++k4) {
      float4 ev = *(float4*)(e32 + 4 * k4);
      float4 tv = *(const float4*)(theta + f * CH + 4 * k4);
      s0 += tv.x * ev.x + tv.z * ev.z;
      s1 += tv.y * ev.y + tv.w * ev.w;
    }
    EF[e * CH + f] = s0 + s1;
  }
}

// ---------------- edge->node CSR gather + finalize (conv1) ----------------
__global__ __launch_bounds__(256) void node_gather_kernel(
    const float* __restrict__ EF, const int* __restrict__ NOFF,
    const int* __restrict__ INCN, const float* __restrict__ bias,
    float* __restrict__ X)
{
  int gid = blockIdx.x * 256 + threadIdx.x;
  if (gid >= N_NODES * 8) return;
  int n = gid >> 3, q = gid & 7;
  int s = NOFF[n], e = NOFF[n + 1];
  float4 acc = make_float4(0.f, 0.f, 0.f, 0.f);
  float4 acc2 = make_float4(0.f, 0.f, 0.f, 0.f);
  int k = s;
  for (; k + 1 < e; k += 2) {
    int e0 = INCN[k], e1 = INCN[k + 1];
    float4 v0 = *(const float4*)(EF + e0 * CH + q * 4);
    float4 v1 = *(const float4*)(EF + e1 * CH + q * 4);
    acc.x += v0.x; acc.y += v0.y; acc.z += v0.z; acc.w += v0.w;
    acc2.x += v1.x; acc2.y += v1.y; acc2.z += v1.z; acc2.w += v1.w;
  }
  if (k < e) {
    float4 v0 = *(const float4*)(EF + INCN[k] * CH + q * 4);
    acc.x += v0.x; acc.y += v0.y; acc.z += v0.z; acc.w += v0.w;
  }
  int d = e - s;
  float dinv = d > 0 ? 1.f / (float)d : 0.f;
  float4 b = *(const float4*)(bias + 4 * q);
  float4 o;
  o.x = leaky(fmaf(acc.x + acc2.x, dinv, b.x));
  o.y = leaky(fmaf(acc.y + acc2.y, dinv, b.y));
  o.z = leaky(fmaf(acc.z + acc2.z, dinv, b.z));
  o.w = leaky(fmaf(acc.w + acc2.w, dinv, b.w));
  *(float4*)(X + n * CH + 4 * q) = o;
}

// ---------------- edge->node CSR gather + finalize + output linear (conv2) ----------------
__global__ __launch_bounds__(256) void node_gather_out_kernel(
    const float* __restrict__ EF, const int* __restrict__ NOFF,
    const int* __restrict__ INCN, const float* __restrict__ bias,
    const float* __restrict__ w_out, const float* __restrict__ b_out,
    float* __restrict__ out)
{
  int gid = blockIdx.x * 256 + threadIdx.x;
  if (gid >= N_NODES * 8) return;
  int n = gid >> 3, q = gid & 7;
  int s = NOFF[n], e = NOFF[n + 1];
  float4 acc = make_float4(0.f, 0.f, 0.f, 0.f);
  float4 acc2 = make_float4(0.f, 0.f, 0.f, 0.f);
  int k = s;
  for (; k + 1 < e; k += 2) {
    int e0 = INCN[k], e1 = INCN[k + 1];
    float4 v0 = *(const float4*)(EF + e0 * CH + q * 4);
    float4 v1 = *(const float4*)(EF + e1 * CH + q * 4);
    acc.x += v0.x; acc.y += v0.y; acc.z += v0.z; acc.w += v0.w;
    acc2.x += v1.x; acc2.y += v1.y; acc2.z += v1.z; acc2.w += v1.w;
  }
  if (k < e) {
    float4 v0 = *(const float4*)(EF + INCN[k] * CH + q * 4);
    acc.x += v0.x; acc.y += v0.y; acc.z += v0.z; acc.w += v0.w;
  }
  int d = e - s;
  float dinv = d > 0 ? 1.f / (float)d : 0.f;
  float4 b = *(const float4*)(bias + 4 * q);
  float v0 = leaky(fmaf(acc.x + acc2.x, dinv, b.x));
  float v1 = leaky(fmaf(acc.y + acc2.y, dinv, b.y));
  float v2 = leaky(fmaf(acc.z + acc2.z, dinv, b.z));
  float v3 = leaky(fmaf(acc.w + acc2.w, dinv, b.w));

  // partial 32->5 linear over this quad, then 8-lane xor reduce
  float p[OUTF];
#pragma unroll
  for (int o = 0; o < OUTF; ++o) {
    const float* wr = w_out + o * CH + 4 * q;
    p[o] = v0 * wr[0] + v1 * wr[1] + v2 * wr[2] + v3 * wr[3];
  }
#pragma unroll
  for (int off = 1; off < 8; off <<= 1) {
#pragma unroll
    for (int o = 0; o < OUTF; ++o) p[o] += __shfl_xor(p[o], off);
  }
  if (q < OUTF) out[n * OUTF + q] = leaky(p[q] + b_out[q]);
}

extern "C" void kernel_launch(void* const* d_in, const int* in_sizes, int n_in,
                              void* d_out, int out_size, void* d_ws, size_t ws_size,
                              hipStream_t stream)
{
  const float* price   = (const float*)d_in[0];
  const int*   e_nodes = (const int*)d_in[1];
  const int*   e_edges = (const int*)d_in[2];
  const float* w_ih    = (const float*)d_in[6];
  const float* w_hh    = (const float*)d_in[7];
  const float* b_ih    = (const float*)d_in[8];
  const float* b_hh    = (const float*)d_in[9];
  const float* theta1  = (const float*)d_in[10];
  const float* bias1   = (const float*)d_in[11];
  const float* theta2  = (const float*)d_in[12];
  const float* bias2   = (const float*)d_in[13];
  const float* w_out   = (const float*)d_in[14];
  const float* b_out   = (const float*)d_in[15];
  float* out = (float*)d_out;

  float* ws   = (float*)d_ws;
  float* Y    = ws;                    // [50000*32] GRU out, reused as conv1 out
  float* EF   = ws + 1600000;          // [2000*32]
  int*   DN   = (int*)(ws + 1664000);  // [50000]
  int*   DE   = DN + N_NODES;          // [2000]
  int*   OFF  = DE + N_EDGESC;         // [2001]
  int*   NOFF = OFF + N_EDGESC + 1;    // [50001]
  int*   CUR  = NOFF + N_NODES + 1;    // [50000]
  int*   INCN = CUR + N_NODES;         // [200000]

  hipMemsetAsync(DN, 0, (N_NODES + N_EDGESC) * sizeof(int), stream);
  deg_kernel<<<(N_INC + 255) / 256, 256, 0, stream>>>(e_nodes, e_edges, DN, DE);
  scan_kernel<<<1, 256, 0, stream>>>(DE, OFF);
  nscan_kernel<<<1, 1024, 0, stream>>>(DN, NOFF, CUR);
  bucket_kernel<<<(N_INC + 255) / 256, 256, 0, stream>>>(e_nodes, e_edges, CUR, INCN);

  gru_mfma_kernel<<<(N_NODES + 63) / 64, 256, 0, stream>>>(
      price, w_ih, w_hh, b_ih, b_hh, Y);

  // conv1: node->edge (+theta1), edge->node CSR gather (+bias1+leaky)
  edge_gather_kernel<<<N_EDGESC, 256, 0, stream>>>(Y, e_nodes, OFF, theta1, EF);
  node_gather_kernel<<<(N_NODES * 8 + 255) / 256, 256, 0, stream>>>(EF, NOFF, INCN, bias1, Y);

  // conv2: node->edge (+theta2), edge->node CSR gather (+bias2+leaky+w_out+b_out)
  edge_gather_kernel<<<N_EDGESC, 256, 0, stream>>>(Y, e_nodes, OFF, theta2, EF);
  node_gather_out_kernel<<<(N_NODES * 8 + 255) / 256, 256, 0, stream>>>(
      EF, NOFF, INCN, bias2, w_out, b_out, out);
}

// Round 8
// 363.212 us; speedup vs baseline: 2.3378x; 1.0468x over previous
//
#include <hip/hip_runtime.h>
#include <math.h>

#define N_NODES 50000
#define N_EDGESC 2000
#define N_INC   200000
#define SEQ     64
#define FEATN   6
#define CH      32
#define OUTF    5
#define SLOPE   0.01f

typedef __attribute__((ext_vector_type(8))) short bf16x8;
typedef __attribute__((ext_vector_type(4))) float f32x4;

__device__ __forceinline__ float fast_rcp(float x) { return __builtin_amdgcn_rcpf(x); }
__device__ __forceinline__ float sigm(float x) { return fast_rcp(1.f + __expf(-x)); }
__device__ __forceinline__ float tanh_fast(float x) { return 1.f - 2.f * fast_rcp(1.f + __expf(2.f * x)); }
__device__ __forceinline__ float leaky(float v) { return v > 0.f ? v : SLOPE * v; }

__device__ __forceinline__ ushort f2bf(float x) {
  uint u = __float_as_uint(x);
  u = u + 0x7fffu + ((u >> 16) & 1u);
  return (ushort)(u >> 16);
}
__device__ __forceinline__ float bf2f(ushort s) {
  return __uint_as_float(((uint)s) << 16);
}
__device__ __forceinline__ uint pk_bf16(float a, float b) {
  uint r;
  asm("v_cvt_pk_bf16_f32 %0, %1, %2" : "=v"(r) : "v"(a), "v"(b));
  return r;
}

// MFMA with A pinned in AGPRs (gfx950 reads A directly from AGPR -> no
// v_accvgpr_read copies when the weight fragments spill to the AGPR file).
// mfma_z: fresh D, C is a persistent zero quad (not re-materialized per step).
__device__ __forceinline__ f32x4 mfma_z(bf16x8 a, bf16x8 b, f32x4 c) {
  f32x4 d;
  asm("v_mfma_f32_16x16x32_bf16 %0, %1, %2, %3" : "=v"(d) : "a"(a), "v"(b), "v"(c));
  return d;
}
// mfma_acc: in-place accumulate (D tied to C).
__device__ __forceinline__ f32x4 mfma_acc(bf16x8 a, bf16x8 b, f32x4 c) {
  f32x4 d;
  asm("v_mfma_f32_16x16x32_bf16 %0, %1, %2, %3" : "=v"(d) : "a"(a), "v"(b), "0"(c));
  return d;
}

union BW { bf16x8 v; uint w[4]; uint2 d[2]; };

// ---------------- GRU via MFMA (round-8: AGPR-pinned A operands) ----------------
__global__ __launch_bounds__(256) void gru_mfma_kernel(
    const float* __restrict__ price,
    const float* __restrict__ w_ih, const float* __restrict__ w_hh,
    const float* __restrict__ b_ih, const float* __restrict__ b_hh,
    float* __restrict__ Y)
{
  __shared__ __align__(16) ushort Hhi[4][16 * 40];
  __shared__ __align__(16) ushort Hlo[4][16 * 40];

  const int tid  = threadIdx.x;
  const int wid  = tid >> 6;
  const int lane = tid & 63;
  const int q    = lane >> 4;
  const int m    = lane & 15;
  const int node = blockIdx.x * 64 + wid * 16 + m;
  const int nodeC = node < N_NODES ? node : 0;

  ushort* Hh = &Hhi[wid][0];
  ushort* Hl = &Hlo[wid][0];

  bf16x8 WAhi[6], WAlo[6];
#pragma unroll
  for (int tt = 0; tt < 6; ++tt) {
    const float* wr = w_hh + (tt * 16 + m) * CH + 8 * q;
    float4 v0 = *(const float4*)(wr);
    float4 v1 = *(const float4*)(wr + 4);
    float vv[8] = {v0.x, v0.y, v0.z, v0.w, v1.x, v1.y, v1.z, v1.w};
#pragma unroll
    for (int e = 0; e < 8; ++e) {
      ushort h = f2bf(vv[e]);
      WAhi[tt][e] = (short)h;
      WAlo[tt][e] = (short)f2bf(vv[e] - bf2f(h));
    }
  }

  bf16x8 GA[6];
#pragma unroll
  for (int tt = 0; tt < 6; ++tt) {
    int g = tt * 16 + m;
    bf16x8 a = {0, 0, 0, 0, 0, 0, 0, 0};
    if (q < 3) {
      float w[6];
#pragma unroll
      for (int f = 0; f < FEATN; ++f) w[f] = w_ih[g * FEATN + f];
      ushort wh[6]; float wl[6];
#pragma unroll
      for (int f = 0; f < FEATN; ++f) { wh[f] = f2bf(w[f]); wl[f] = w[f] - bf2f(wh[f]); }
      if (q == 0) {
#pragma unroll
        for (int f = 0; f < 6; ++f) a[f] = (short)wh[f];
        a[6] = (short)wh[0]; a[7] = (short)wh[1];
      } else if (q == 1) {
#pragma unroll
        for (int f = 0; f < 4; ++f) a[f] = (short)wh[2 + f];
#pragma unroll
        for (int f = 0; f < 4; ++f) a[4 + f] = (short)f2bf(wl[f]);
      } else {
        a[0] = (short)f2bf(wl[4]);
        a[1] = (short)f2bf(wl[5]);
        float bias = b_ih[g] + (g < 64 ? b_hh[g] : 0.f);
        ushort bh = f2bf(bias);
        a[2] = (short)bh;
        a[3] = (short)f2bf(bias - bf2f(bh));
      }
    }
    GA[tt] = a;
  }

  float bhn[8];
#pragma unroll
  for (int i = 0; i < 4; ++i) {
    bhn[i]     = b_hh[64 + 4 * q + i];
    bhn[4 + i] = b_hh[80 + 4 * q + i];
  }

  {
    uint2 z; z.x = 0; z.y = 0;
    *(uint2*)(Hh + m * 40 + 4 * q) = z;
    *(uint2*)(Hh + m * 40 + 16 + 4 * q) = z;
    *(uint2*)(Hl + m * 40 + 4 * q) = z;
    *(uint2*)(Hl + m * 40 + 16 + 4 * q) = z;
  }

  float h_f32[8];
#pragma unroll
  for (int i = 0; i < 8; ++i) h_f32[i] = 0.f;

  const float* xp = price + nodeC * (SEQ * FEATN);
  float xc[6], xn[6];
  if (q < 3) {
    float2 a0 = *(const float2*)(xp);
    float2 a1 = *(const float2*)(xp + 2);
    float2 a2 = *(const float2*)(xp + 4);
    xc[0] = a0.x; xc[1] = a0.y; xc[2] = a1.x; xc[3] = a1.y; xc[4] = a2.x; xc[5] = a2.y;
  }

  const f32x4 zz = {0.f, 0.f, 0.f, 0.f};

  for (int t = 0; t < SEQ; ++t) {
    BW bx; bx.w[0] = 0; bx.w[1] = 0; bx.w[2] = 0; bx.w[3] = 0;
    if (q < 3) {
      uint p01 = pk_bf16(xc[0], xc[1]);
      uint p23 = pk_bf16(xc[2], xc[3]);
      uint p45 = pk_bf16(xc[4], xc[5]);
      float l0 = xc[0] - __uint_as_float(p01 << 16);
      float l1 = xc[1] - __uint_as_float(p01 & 0xFFFF0000u);
      float l2 = xc[2] - __uint_as_float(p23 << 16);
      float l3 = xc[3] - __uint_as_float(p23 & 0xFFFF0000u);
      float l4 = xc[4] - __uint_as_float(p45 << 16);
      float l5 = xc[5] - __uint_as_float(p45 & 0xFFFF0000u);
      if (q == 0) {
        bx.w[0] = p01; bx.w[1] = p23; bx.w[2] = p45;
        bx.w[3] = pk_bf16(l0, l1);
      } else if (q == 1) {
        bx.w[0] = pk_bf16(l2, l3); bx.w[1] = pk_bf16(l4, l5);
        bx.w[2] = p01; bx.w[3] = p23;
      } else {
        bx.w[0] = p45; bx.w[1] = 0x3F803F80u;
      }
    }
    bf16x8 Bx = bx.v;

    if (t + 1 < SEQ && q < 3) {
      const float* nx = xp + (t + 1) * FEATN;
      float2 a0 = *(const float2*)(nx);
      float2 a1 = *(const float2*)(nx + 2);
      float2 a2 = *(const float2*)(nx + 4);
      xn[0] = a0.x; xn[1] = a0.y; xn[2] = a1.x; xn[3] = a1.y; xn[4] = a2.x; xn[5] = a2.y;
    }

    bf16x8 HhF = *(bf16x8*)(Hh + m * 40 + 8 * q);
    bf16x8 HlF = *(bf16x8*)(Hl + m * 40 + 8 * q);

    f32x4 aRZ[4], aNh[2], aNi[2];
#pragma unroll
    for (int tt = 0; tt < 4; ++tt) {
      f32x4 a = mfma_z(GA[tt], Bx, zz);
      a = mfma_acc(WAlo[tt], HhF, a);
      a = mfma_acc(WAhi[tt], HlF, a);
      a = mfma_acc(WAhi[tt], HhF, a);
      aRZ[tt] = a;
    }
#pragma unroll
    for (int tt = 0; tt < 2; ++tt) {
      f32x4 a = mfma_z(WAlo[4 + tt], HhF, zz);
      a = mfma_acc(WAhi[4 + tt], HlF, a);
      a = mfma_acc(WAhi[4 + tt], HhF, a);
      aNh[tt] = a;
      aNi[tt] = mfma_z(GA[4 + tt], Bx, zz);
    }

    float hv[8];
#pragma unroll
    for (int s = 0; s < 2; ++s) {
#pragma unroll
      for (int i = 0; i < 4; ++i) {
        int u = s * 4 + i;
        float r  = sigm(aRZ[s][i]);
        float z  = sigm(aRZ[2 + s][i]);
        float n  = tanh_fast(aNi[s][i] + r * (aNh[s][i] + bhn[u]));
        float h2 = n + z * (h_f32[u] - n);
        h_f32[u] = h2;
        hv[u] = h2;
      }
    }

    uint ph0 = pk_bf16(hv[0], hv[1]);
    uint ph1 = pk_bf16(hv[2], hv[3]);
    uint ph2 = pk_bf16(hv[4], hv[5]);
    uint ph3 = pk_bf16(hv[6], hv[7]);
    float l0 = hv[0] - __uint_as_float(ph0 << 16);
    float l1 = hv[1] - __uint_as_float(ph0 & 0xFFFF0000u);
    float l2 = hv[2] - __uint_as_float(ph1 << 16);
    float l3 = hv[3] - __uint_as_float(ph1 & 0xFFFF0000u);
    float l4 = hv[4] - __uint_as_float(ph2 << 16);
    float l5 = hv[5] - __uint_as_float(ph2 & 0xFFFF0000u);
    float l6 = hv[6] - __uint_as_float(ph3 << 16);
    float l7 = hv[7] - __uint_as_float(ph3 & 0xFFFF0000u);
    uint2 wa, wb;
    wa.x = ph0; wa.y = ph1; wb.x = ph2; wb.y = ph3;
    *(uint2*)(Hh + m * 40 + 4 * q) = wa;
    *(uint2*)(Hh + m * 40 + 16 + 4 * q) = wb;
    wa.x = pk_bf16(l0, l1); wa.y = pk_bf16(l2, l3);
    wb.x = pk_bf16(l4, l5); wb.y = pk_bf16(l6, l7);
    *(uint2*)(Hl + m * 40 + 4 * q) = wa;
    *(uint2*)(Hl + m * 40 + 16 + 4 * q) = wb;

    if (q < 3) {
#pragma unroll
      for (int f = 0; f < 6; ++f) xc[f] = xn[f];
    }
  }

  {
    int mm = lane >> 2, c = lane & 3;
    int onode = blockIdx.x * 64 + wid * 16 + mm;
    if (onode < N_NODES) {
      bf16x8 vh = *(bf16x8*)(Hh + mm * 40 + c * 8);
      bf16x8 vl = *(bf16x8*)(Hl + mm * 40 + c * 8);
      float o[8];
#pragma unroll
      for (int e = 0; e < 8; ++e) o[e] = bf2f((ushort)vh[e]) + bf2f((ushort)vl[e]);
      float4 o0; o0.x = o[0]; o0.y = o[1]; o0.z = o[2]; o0.w = o[3];
      float4 o1; o1.x = o[4]; o1.y = o[5]; o1.z = o[6]; o1.w = o[7];
      *(float4*)(Y + onode * CH + c * 8) = o0;
      *(float4*)(Y + onode * CH + c * 8 + 4) = o1;
    }
  }
}

// ---------------- degree counting ----------------
__global__ __launch_bounds__(256) void deg_kernel(
    const int* __restrict__ nodes, const int* __restrict__ edges,
    int* __restrict__ DN, int* __restrict__ DE)
{
  int i = blockIdx.x * 256 + threadIdx.x;
  if (i < N_INC) {
    atomicAdd(&DN[nodes[i]], 1);
    atomicAdd(&DE[edges[i]], 1);
  }
}

// ---------------- exclusive scan of edge degrees (single block, 2000) ----------------
__global__ __launch_bounds__(256) void scan_kernel(const int* __restrict__ DE, int* __restrict__ OFF)
{
  __shared__ int part[256];
  int t = threadIdx.x;
  int c[8]; int sum = 0;
#pragma unroll
  for (int u = 0; u < 8; ++u) {
    int idx = t * 8 + u;
    int x = (idx < N_EDGESC) ? DE[idx] : 0;
    c[u] = x; sum += x;
  }
  part[t] = sum;
  __syncthreads();
  for (int d = 1; d < 256; d <<= 1) {
    int v = (t >= d) ? part[t - d] : 0;
    __syncthreads();
    part[t] += v;
    __syncthreads();
  }
  int base = part[t] - sum;
#pragma unroll
  for (int u = 0; u < 8; ++u) {
    int idx = t * 8 + u;
    if (idx <= N_EDGESC) OFF[idx] = base;
    base += c[u];
  }
}

// ---------------- exclusive scan of node degrees (single block 1024, 50000) ----------------
#define NPER 49  // 1024*49 >= 50000
__global__ __launch_bounds__(1024) void nscan_kernel(
    const int* __restrict__ DN, int* __restrict__ NOFF, int* __restrict__ CUR)
{
  __shared__ int part[1024];
  int t = threadIdx.x;
  int cl[NPER]; int sum = 0;
  int base_i = t * NPER;
#pragma unroll
  for (int u = 0; u < NPER; ++u) {
    int idx = base_i + u;
    int x = (idx < N_NODES) ? DN[idx] : 0;
    cl[u] = x; sum += x;
  }
  part[t] = sum;
  __syncthreads();
  for (int d = 1; d < 1024; d <<= 1) {
    int v = (t >= d) ? part[t - d] : 0;
    __syncthreads();
    part[t] += v;
    __syncthreads();
  }
  int run = part[t] - sum;  // exclusive
#pragma unroll
  for (int u = 0; u < NPER; ++u) {
    int idx = base_i + u;
    if (idx < N_NODES) { NOFF[idx] = run; CUR[idx] = run; }
    run += cl[u];
  }
  if (t == 1023) NOFF[N_NODES] = run;
}

// ---------------- bucket incidences by node: INCN[pos] = edge ----------------
__global__ __launch_bounds__(256) void bucket_kernel(
    const int* __restrict__ nodes, const int* __restrict__ edges,
    int* __restrict__ CUR, int* __restrict__ INCN)
{
  int i = blockIdx.x * 256 + threadIdx.x;
  if (i < N_INC) {
    int p = atomicAdd(&CUR[nodes[i]], 1);
    INCN[p] = edges[i];
  }
}

// ---------------- node->edge gather-sum + fused theta (256 thr, 2-way ILP) ----------------
__global__ __launch_bounds__(256) void edge_gather_kernel(
    const float* __restrict__ X, const int* __restrict__ nodes,
    const int* __restrict__ OFF, const float* __restrict__ theta,
    float* __restrict__ EF)
{
  int e = blockIdx.x;
  int s = OFF[e], tE = OFF[e + 1];
  int f = threadIdx.x & 31, g = threadIdx.x >> 5;  // 8 row-groups
  float a0 = 0.f, a1 = 0.f;
  for (int i = s + g; i < tE; i += 16) {
    a0 += X[nodes[i] * CH + f];
    if (i + 8 < tE) a1 += X[nodes[i + 8] * CH + f];
  }
  __shared__ float red[8][33];
  __shared__ __align__(16) float e32[32];
  red[g][f] = a0 + a1;
  __syncthreads();
  if (threadIdx.x < 32) {
    float acc = 0.f;
#pragma unroll
    for (int r = 0; r < 8; ++r) acc += red[r][f];
    int cnt = tE - s;
    float binv = cnt > 0 ? 1.f / (float)cnt : 0.f;
    e32[f] = acc * binv;
    float s0 = 0.f, s1 = 0.f;
#pragma unroll
    for (int k4 = 0; k4 < 8; ++k4) {
      float4 ev = *(float4*)(e32 + 4 * k4);
      float4 tv = *(const float4*)(theta + f * CH + 4 * k4);
      s0 += tv.x * ev.x + tv.z * ev.z;
      s1 += tv.y * ev.y + tv.w * ev.w;
    }
    EF[e * CH + f] = s0 + s1;
  }
}

// ---------------- edge->node CSR gather + finalize (conv1) ----------------
__global__ __launch_bounds__(256) void node_gather_kernel(
    const float* __restrict__ EF, const int* __restrict__ NOFF,
    const int* __restrict__ INCN, const float* __restrict__ bias,
    float* __restrict__ X)
{
  int gid = blockIdx.x * 256 + threadIdx.x;
  if (gid >= N_NODES * 8) return;
  int n = gid >> 3, q = gid & 7;
  int s = NOFF[n], e = NOFF[n + 1];
  float4 acc = make_float4(0.f, 0.f, 0.f, 0.f);
  float4 acc2 = make_float4(0.f, 0.f, 0.f, 0.f);
  int k = s;
  for (; k + 1 < e; k += 2) {
    int e0 = INCN[k], e1 = INCN[k + 1];
    float4 v0 = *(const float4*)(EF + e0 * CH + q * 4);
    float4 v1 = *(const float4*)(EF + e1 * CH + q * 4);
    acc.x += v0.x; acc.y += v0.y; acc.z += v0.z; acc.w += v0.w;
    acc2.x += v1.x; acc2.y += v1.y; acc2.z += v1.z; acc2.w += v1.w;
  }
  if (k < e) {
    float4 v0 = *(const float4*)(EF + INCN[k] * CH + q * 4);
    acc.x += v0.x; acc.y += v0.y; acc.z += v0.z; acc.w += v0.w;
  }
  int d = e - s;
  float dinv = d > 0 ? 1.f / (float)d : 0.f;
  float4 b = *(const float4*)(bias + 4 * q);
  float4 o;
  o.x = leaky(fmaf(acc.x + acc2.x, dinv, b.x));
  o.y = leaky(fmaf(acc.y + acc2.y, dinv, b.y));
  o.z = leaky(fmaf(acc.z + acc2.z, dinv, b.z));
  o.w = leaky(fmaf(acc.w + acc2.w, dinv, b.w));
  *(float4*)(X + n * CH + 4 * q) = o;
}

// ---------------- edge->node CSR gather + finalize + output linear (conv2) ----------------
__global__ __launch_bounds__(256) void node_gather_out_kernel(
    const float* __restrict__ EF, const int* __restrict__ NOFF,
    const int* __restrict__ INCN, const float* __restrict__ bias,
    const float* __restrict__ w_out, const float* __restrict__ b_out,
    float* __restrict__ out)
{
  int gid = blockIdx.x * 256 + threadIdx.x;
  if (gid >= N_NODES * 8) return;
  int n = gid >> 3, q = gid & 7;
  int s = NOFF[n], e = NOFF[n + 1];
  float4 acc = make_float4(0.f, 0.f, 0.f, 0.f);
  float4 acc2 = make_float4(0.f, 0.f, 0.f, 0.f);
  int k = s;
  for (; k + 1 < e; k += 2) {
    int e0 = INCN[k], e1 = INCN[k + 1];
    float4 v0 = *(const float4*)(EF + e0 * CH + q * 4);
    float4 v1 = *(const float4*)(EF + e1 * CH + q * 4);
    acc.x += v0.x; acc.y += v0.y; acc.z += v0.z; acc.w += v0.w;
    acc2.x += v1.x; acc2.y += v1.y; acc2.z += v1.z; acc2.w += v1.w;
  }
  if (k < e) {
    float4 v0 = *(const float4*)(EF + INCN[k] * CH + q * 4);
    acc.x += v0.x; acc.y += v0.y; acc.z += v0.z; acc.w += v0.w;
  }
  int d = e - s;
  float dinv = d > 0 ? 1.f / (float)d : 0.f;
  float4 b = *(const float4*)(bias + 4 * q);
  float v0 = leaky(fmaf(acc.x + acc2.x, dinv, b.x));
  float v1 = leaky(fmaf(acc.y + acc2.y, dinv, b.y));
  float v2 = leaky(fmaf(acc.z + acc2.z, dinv, b.z));
  float v3 = leaky(fmaf(acc.w + acc2.w, dinv, b.w));

  float p[OUTF];
#pragma unroll
  for (int o = 0; o < OUTF; ++o) {
    const float* wr = w_out + o * CH + 4 * q;
    p[o] = v0 * wr[0] + v1 * wr[1] + v2 * wr[2] + v3 * wr[3];
  }
#pragma unroll
  for (int off = 1; off < 8; off <<= 1) {
#pragma unroll
    for (int o = 0; o < OUTF; ++o) p[o] += __shfl_xor(p[o], off);
  }
  if (q < OUTF) out[n * OUTF + q] = leaky(p[q] + b_out[q]);
}

extern "C" void kernel_launch(void* const* d_in, const int* in_sizes, int n_in,
                              void* d_out, int out_size, void* d_ws, size_t ws_size,
                              hipStream_t stream)
{
  const float* price   = (const float*)d_in[0];
  const int*   e_nodes = (const int*)d_in[1];
  const int*   e_edges = (const int*)d_in[2];
  const float* w_ih    = (const float*)d_in[6];
  const float* w_hh    = (const float*)d_in[7];
  const float* b_ih    = (const float*)d_in[8];
  const float* b_hh    = (const float*)d_in[9];
  const float* theta1  = (const float*)d_in[10];
  const float* bias1   = (const float*)d_in[11];
  const float* theta2  = (const float*)d_in[12];
  const float* bias2   = (const float*)d_in[13];
  const float* w_out   = (const float*)d_in[14];
  const float* b_out   = (const float*)d_in[15];
  float* out = (float*)d_out;

  float* ws   = (float*)d_ws;
  float* Y    = ws;                    // [50000*32]
  float* EF   = ws + 1600000;          // [2000*32]
  int*   DN   = (int*)(ws + 1664000);  // [50000]
  int*   DE   = DN + N_NODES;          // [2000]
  int*   OFF  = DE + N_EDGESC;         // [2001]
  int*   NOFF = OFF + N_EDGESC + 1;    // [50001]
  int*   CUR  = NOFF + N_NODES + 1;    // [50000]
  int*   INCN = CUR + N_NODES;         // [200000]

  hipMemsetAsync(DN, 0, (N_NODES + N_EDGESC) * sizeof(int), stream);
  deg_kernel<<<(N_INC + 255) / 256, 256, 0, stream>>>(e_nodes, e_edges, DN, DE);
  scan_kernel<<<1, 256, 0, stream>>>(DE, OFF);
  nscan_kernel<<<1, 1024, 0, stream>>>(DN, NOFF, CUR);
  bucket_kernel<<<(N_INC + 255) / 256, 256, 0, stream>>>(e_nodes, e_edges, CUR, INCN);

  gru_mfma_kernel<<<(N_NODES + 63) / 64, 256, 0, stream>>>(
      price, w_ih, w_hh, b_ih, b_hh, Y);

  // conv1: node->edge (+theta1), edge->node CSR gather (+bias1+leaky)
  edge_gather_kernel<<<N_EDGESC, 256, 0, stream>>>(Y, e_nodes, OFF, theta1, EF);
  node_gather_kernel<<<(N_NODES * 8 + 255) / 256, 256, 0, stream>>>(EF, NOFF, INCN, bias1, Y);

  // conv2: node->edge (+theta2), edge->node CSR gather (+bias2+leaky+w_out+b_out)
  edge_gather_kernel<<<N_EDGESC, 256, 0, stream>>>(Y, e_nodes, OFF, theta2, EF);
  node_gather_out_kernel<<<(N_NODES * 8 + 255) / 256, 256, 0, stream>>>(
      EF, NOFF, INCN, bias2, w_out, b_out, out);
}